// Round 6
// baseline (269.315 us; speedup 1.0000x reference)
//
#include <hip/hip_runtime.h>

#define NN 100000
#define NE 1600000
#define SCAN_B 1024
#define NSEG 6250         // NN/16 target-node segments (one wave each)

// bucketed counting sort params: 512 nodes per bucket
#define BSH 9
#define BSZ 512
#define NBUK 196          // ceil(NN / BSZ)
#define CAP 12288         // per-bucket pair capacity (mean 8163, huge margin)
#define CHUNK 4096        // edges per block in k_bucket

typedef short bs8 __attribute__((ext_vector_type(8)));
typedef float f32x4 __attribute__((ext_vector_type(4)));
#define MFMA16(a, b, c) __builtin_amdgcn_mfma_f32_16x16x32_bf16(a, b, c, 0, 0, 0)

static inline size_t alignup(size_t x) { return (x + 255) & ~(size_t)255; }

__device__ __forceinline__ ushort f2bf(float f) {  // RNE, finite inputs
  uint u = __float_as_uint(f);
  u += 0x7fffu + ((u >> 16) & 1u);
  return (ushort)(u >> 16);
}

// ---------------- graph prep (bucketed counting sort) ----------------

// fused: gcur init + W1/W2 fp32->bf16 transposed converts
__global__ __launch_bounds__(256) void k_prep0(int* __restrict__ gcur,
                                               const float* __restrict__ W1, ushort* __restrict__ WT1,
                                               const float* __restrict__ W2, ushort* __restrict__ WT2) {
  int b = blockIdx.x, t = threadIdx.x;
  if (b < 64) {  // W1: [128,128] -> WT1[c][k]
    int i = b * 256 + t;
    int k = i >> 7, c = i & 127;
    WT1[c * 128 + k] = f2bf(W1[i]);
  } else if (b < 96) {  // W2: [128,64] -> WT2[c][k]
    int i = (b - 64) * 256 + t;
    int k = i >> 6, c = i & 63;
    WT2[c * 128 + k] = f2bf(W2[i]);
  } else {
    if (t < NBUK) gcur[t] = t * CAP;
  }
}

// bin edges into buckets: block-level two-phase (LDS hist -> global reserve -> append)
__global__ __launch_bounds__(256) void k_bucket(const int* __restrict__ row, const int* __restrict__ col,
                                                int* __restrict__ gcur, uint* __restrict__ pr_row,
                                                ushort* __restrict__ pr_li) {
  __shared__ int cnt[NBUK];
  int t = threadIdx.x;
  for (int i = t; i < NBUK; i += 256) cnt[i] = 0;
  __syncthreads();
  int e0 = blockIdx.x * CHUNK;
  int e1 = min(e0 + CHUNK, NE);
  for (int e = e0 + t; e < e1; e += 256) atomicAdd(&cnt[col[e] >> BSH], 1);
  __syncthreads();
  for (int i = t; i < NBUK; i += 256) {
    int c = cnt[i];
    cnt[i] = c ? atomicAdd(&gcur[i], c) : 0;
  }
  __syncthreads();
  for (int e = e0 + t; e < e1; e += 256) {
    int c = col[e];
    int p = atomicAdd(&cnt[c >> BSH], 1);
    pr_row[p] = (uint)row[e];
    pr_li[p] = (ushort)(c & (BSZ - 1));
  }
}

// per-bucket degree count (+1 self loop) fused with dinv
__global__ __launch_bounds__(256) void k_bdeg(const ushort* __restrict__ pr_li, const int* __restrict__ gcur,
                                              int* __restrict__ deg, float* __restrict__ dinv) {
  __shared__ int dc[BSZ];
  int t = threadIdx.x, b = blockIdx.x;
  for (int i = t; i < BSZ; i += 256) dc[i] = 0;
  __syncthreads();
  int s = b * CAP;
  int n = min(gcur[b] - s, CAP);
  for (int i = t; i < n; i += 256) atomicAdd(&dc[pr_li[s + i]], 1);
  __syncthreads();
  int nb0 = b << BSH;
  for (int i = t; i < BSZ; i += 256) {
    int node = nb0 + i;
    if (node < NN) {
      int d = dc[i] + 1;
      deg[node] = d;
      dinv[node] = rsqrtf((float)d);
    }
  }
}

// exclusive scan of deg (WITH self-loops) -> offs; CSR holds NE+NN entries
__global__ __launch_bounds__(SCAN_B) void k_scan1(const int* __restrict__ deg, int* __restrict__ offs,
                                                  int* __restrict__ bsums) {
  __shared__ int sm[SCAN_B];
  int i = blockIdx.x * SCAN_B + threadIdx.x;
  int v = (i < NN) ? deg[i] : 0;
  sm[threadIdx.x] = v;
  __syncthreads();
  for (int d = 1; d < SCAN_B; d <<= 1) {
    int t = (threadIdx.x >= d) ? sm[threadIdx.x - d] : 0;
    __syncthreads();
    sm[threadIdx.x] += t;
    __syncthreads();
  }
  if (i < NN) offs[i] = sm[threadIdx.x] - v;
  if (threadIdx.x == SCAN_B - 1) bsums[blockIdx.x] = sm[threadIdx.x];
}

__global__ __launch_bounds__(128) void k_scan2(int* __restrict__ bsums, int nb) {
  __shared__ int sm[128];
  int v = (threadIdx.x < nb) ? bsums[threadIdx.x] : 0;
  sm[threadIdx.x] = v;
  __syncthreads();
  for (int d = 1; d < 128; d <<= 1) {
    int t = (threadIdx.x >= d) ? sm[threadIdx.x - d] : 0;
    __syncthreads();
    sm[threadIdx.x] += t;
    __syncthreads();
  }
  if (threadIdx.x < nb) bsums[threadIdx.x] = sm[threadIdx.x] - v;
}

__global__ __launch_bounds__(SCAN_B) void k_scan3(int* __restrict__ offs, const int* __restrict__ bsums) {
  int i = blockIdx.x * SCAN_B + threadIdx.x;
  if (i < NN) offs[i] += bsums[blockIdx.x];
}

// weighted CSR incl. self-loops: entry = (src_row, bf16(w)<<16 | local_target&15)
__global__ __launch_bounds__(256) void k_bfill(const uint* __restrict__ pr_row, const ushort* __restrict__ pr_li,
                                               const int* __restrict__ gcur, const int* __restrict__ offs,
                                               const float* __restrict__ dinv, uint2* __restrict__ wcsr) {
  __shared__ int loff[BSZ];
  __shared__ int cur[BSZ];
  __shared__ float dl[BSZ];
  int t = threadIdx.x, b = blockIdx.x;
  int nb0 = b << BSH;
  for (int i = t; i < BSZ; i += 256) {
    int node = nb0 + i;
    if (node < NN) {
      int o = offs[node];
      float d = dinv[node];
      loff[i] = o;
      dl[i] = d;
      cur[i] = 1;  // slot 0 = self loop
      wcsr[o] = make_uint2((uint)node, ((uint)f2bf(d * d) << 16) | (uint)(i & 15));
    } else {
      loff[i] = 0; dl[i] = 0.f; cur[i] = 1;
    }
  }
  __syncthreads();
  int s = b * CAP;
  int n = min(gcur[b] - s, CAP);
  for (int i = t; i < n; i += 256) {
    int li = pr_li[s + i];
    uint r = pr_row[s + i];
    int p = atomicAdd(&cur[li], 1);
    wcsr[loff[li] + p] = make_uint2(r, ((uint)f2bf(dinv[r] * dl[li]) << 16) | (uint)(li & 15));
  }
}

// ---------------- dense transforms (bf16 MFMA) ----------------

__global__ __launch_bounds__(256) void k_gemm128(const float* __restrict__ x, const ushort* __restrict__ WT,
                                                 ushort* __restrict__ t) {
  int wave = threadIdx.x >> 6, lane = threadIdx.x & 63;
  int col0 = wave * 32;
  int lr = lane & 15;
  int lk = (lane >> 4) * 8;
  bs8 bfrag[2][4];
#pragma unroll
  for (int n = 0; n < 2; n++)
#pragma unroll
    for (int ks = 0; ks < 4; ks++)
      bfrag[n][ks] = *(const bs8*)&WT[(size_t)(col0 + n * 16 + lr) * 128 + ks * 32 + lk];
  int row0 = blockIdx.x * 64;
#pragma unroll 1
  for (int mt = 0; mt < 4; mt++) {
    int r0 = row0 + mt * 16;
    if (r0 >= NN) return;
    const float* xr = x + (size_t)(r0 + lr) * 128 + lk;
    f32x4 acc[2] = {{0.f, 0.f, 0.f, 0.f}, {0.f, 0.f, 0.f, 0.f}};
#pragma unroll
    for (int ks = 0; ks < 4; ks++) {
      float4 a0 = *(const float4*)&xr[ks * 32];
      float4 a1 = *(const float4*)&xr[ks * 32 + 4];
      bs8 af;
      af[0] = (short)f2bf(a0.x); af[1] = (short)f2bf(a0.y);
      af[2] = (short)f2bf(a0.z); af[3] = (short)f2bf(a0.w);
      af[4] = (short)f2bf(a1.x); af[5] = (short)f2bf(a1.y);
      af[6] = (short)f2bf(a1.z); af[7] = (short)f2bf(a1.w);
      acc[0] = MFMA16(af, bfrag[0][ks], acc[0]);
      acc[1] = MFMA16(af, bfrag[1][ks], acc[1]);
    }
    int rbase = r0 + (lane >> 4) * 4;
#pragma unroll
    for (int n = 0; n < 2; n++)
#pragma unroll
      for (int r = 0; r < 4; r++)
        t[(size_t)(rbase + r) * 128 + col0 + n * 16 + lr] = f2bf(acc[n][r]);
  }
}

__global__ __launch_bounds__(256) void k_gemm64(const ushort* __restrict__ h, const ushort* __restrict__ WT,
                                                ushort* __restrict__ t2) {
  int wave = threadIdx.x >> 6, lane = threadIdx.x & 63;
  int col0 = wave * 16;
  int lr = lane & 15;
  int lk = (lane >> 4) * 8;
  bs8 bfrag[4];
#pragma unroll
  for (int ks = 0; ks < 4; ks++)
    bfrag[ks] = *(const bs8*)&WT[(size_t)(col0 + lr) * 128 + ks * 32 + lk];
  int row0 = blockIdx.x * 64;
#pragma unroll 1
  for (int mt = 0; mt < 4; mt++) {
    int r0 = row0 + mt * 16;
    if (r0 >= NN) return;
    const ushort* hr = h + (size_t)(r0 + lr) * 128 + lk;
    f32x4 acc = {0.f, 0.f, 0.f, 0.f};
#pragma unroll
    for (int ks = 0; ks < 4; ks++) {
      bs8 af = *(const bs8*)&hr[ks * 32];
      acc = MFMA16(af, bfrag[ks], acc);
    }
    int rbase = r0 + (lane >> 4) * 4;
#pragma unroll
    for (int r = 0; r < 4; r++)
      t2[(size_t)(rbase + r) * 64 + col0 + lr] = f2bf(acc[r]);
  }
}

// ---------------- MFMA segment aggregation (direct-fragment gathers) ----------------
// One wave owns 16 target nodes. Per 32-slot batch: A = one-hot weights (regs),
// B-frag elements loaded DIRECTLY from global: bf[j] = t[row_{g*8+j}*F + ft*16 + f].

__global__ __launch_bounds__(256) void k_agg128(const ushort* __restrict__ t, const int* __restrict__ offs,
                                                const uint2* __restrict__ wcsr, const float* __restrict__ bias,
                                                ushort* __restrict__ out) {
  int wave = threadIdx.x >> 6, lane = threadIdx.x & 63;
  int seg = blockIdx.x * 4 + wave;
  if (seg >= NSEG) return;
  int seg0 = seg * 16;
  int e0 = offs[seg0];
  int e1 = (seg0 + 16 == NN) ? (NE + NN) : offs[seg0 + 16];
  int sl = lane & 31;
  int g = lane >> 4, f = lane & 15;

  f32x4 acc[8];
#pragma unroll
  for (int i = 0; i < 8; i++) acc[i] = (f32x4){0.f, 0.f, 0.f, 0.f};

  int nb = (e1 - e0 + 31) >> 5;
#pragma unroll 1
  for (int b = 0; b < nb; b++) {
    int p = e0 + b * 32 + sl;
    uint2 e = (p < e1) ? wcsr[p] : make_uint2(0u, 0u);
    const ushort* rp[8];
    bs8 af;
#pragma unroll
    for (int j = 0; j < 8; j++) {
      int src = g * 8 + j;
      uint ex = (uint)__shfl((int)e.x, src);
      uint ey = (uint)__shfl((int)e.y, src);
      af[j] = (short)(((ey & 15u) == (uint)f) ? (ushort)(ey >> 16) : (ushort)0);
      rp[j] = t + (((size_t)ex) << 7) + f;  // row*128 elems + f
    }
#pragma unroll
    for (int ft = 0; ft < 8; ft++) {
      bs8 bf;
#pragma unroll
      for (int j = 0; j < 8; j++) bf[j] = (short)rp[j][ft * 16];
      acc[ft] = MFMA16(af, bf, acc[ft]);
    }
  }
  // C layout: col=f, row=g*4+reg ; add bias, relu, store bf16
#pragma unroll
  for (int ft = 0; ft < 8; ft++) {
    float bb = bias[ft * 16 + f];
#pragma unroll
    for (int r = 0; r < 4; r++) {
      int node = seg0 + g * 4 + r;
      out[(size_t)node * 128 + ft * 16 + f] = f2bf(fmaxf(acc[ft][r] + bb, 0.f));
    }
  }
}

__global__ __launch_bounds__(256) void k_agg64(const ushort* __restrict__ t, const int* __restrict__ offs,
                                               const uint2* __restrict__ wcsr, const float* __restrict__ bias,
                                               float* __restrict__ out) {
  int wave = threadIdx.x >> 6, lane = threadIdx.x & 63;
  int seg = blockIdx.x * 4 + wave;
  if (seg >= NSEG) return;
  int seg0 = seg * 16;
  int e0 = offs[seg0];
  int e1 = (seg0 + 16 == NN) ? (NE + NN) : offs[seg0 + 16];
  int sl = lane & 31;
  int g = lane >> 4, f = lane & 15;

  f32x4 acc[4];
#pragma unroll
  for (int i = 0; i < 4; i++) acc[i] = (f32x4){0.f, 0.f, 0.f, 0.f};

  int nb = (e1 - e0 + 31) >> 5;
#pragma unroll 1
  for (int b = 0; b < nb; b++) {
    int p = e0 + b * 32 + sl;
    uint2 e = (p < e1) ? wcsr[p] : make_uint2(0u, 0u);
    const ushort* rp[8];
    bs8 af;
#pragma unroll
    for (int j = 0; j < 8; j++) {
      int src = g * 8 + j;
      uint ex = (uint)__shfl((int)e.x, src);
      uint ey = (uint)__shfl((int)e.y, src);
      af[j] = (short)(((ey & 15u) == (uint)f) ? (ushort)(ey >> 16) : (ushort)0);
      rp[j] = t + (((size_t)ex) << 6) + f;  // row*64 elems + f
    }
#pragma unroll
    for (int ft = 0; ft < 4; ft++) {
      bs8 bf;
#pragma unroll
      for (int j = 0; j < 8; j++) bf[j] = (short)rp[j][ft * 16];
      acc[ft] = MFMA16(af, bf, acc[ft]);
    }
  }
#pragma unroll
  for (int ft = 0; ft < 4; ft++) {
    float bb = bias[ft * 16 + f];
#pragma unroll
    for (int r = 0; r < 4; r++) {
      int node = seg0 + g * 4 + r;
      out[(size_t)node * 64 + ft * 16 + f] = acc[ft][r] + bb;
    }
  }
}

// ---------------- host ----------------

extern "C" void kernel_launch(void* const* d_in, const int* in_sizes, int n_in,
                              void* d_out, int out_size, void* d_ws, size_t ws_size,
                              hipStream_t stream) {
  const float* x  = (const float*)d_in[0];
  const int*   ei = (const int*)d_in[1];
  const float* W1 = (const float*)d_in[2];
  const float* b1 = (const float*)d_in[3];
  const float* W2 = (const float*)d_in[4];
  const float* b2 = (const float*)d_in[5];
  float* out = (float*)d_out;

  char* p = (char*)d_ws;
  int* deg      = (int*)p;    p += alignup((size_t)NN * 4);
  int* gcur     = (int*)p;    p += alignup((size_t)NBUK * 4);
  int* offs     = (int*)p;    p += alignup((size_t)NN * 4);
  int* bsums    = (int*)p;    p += alignup(128 * 4);
  float* dinv   = (float*)p;  p += alignup((size_t)NN * 4);
  uint2* wcsr   = (uint2*)p;  p += alignup((size_t)(NE + NN) * 8);
  ushort* WT1   = (ushort*)p; p += alignup(128 * 128 * 2);
  ushort* WT2   = (ushort*)p; p += alignup(64 * 128 * 2);
  ushort* t     = (ushort*)p; p += alignup((size_t)NN * 128 * 2);  // reused for t2
  ushort* h1    = (ushort*)p; p += alignup((size_t)NN * 128 * 2);
  // pair buffers alias t (dead before k_gemm128 writes t)
  uint* pr_row  = (uint*)t;
  ushort* pr_li = (ushort*)((char*)t + alignup((size_t)NBUK * CAP * 4));
  (void)ws_size; (void)in_sizes; (void)n_in; (void)out_size;

  const int* row = ei;
  const int* col = ei + NE;

  int nbScan = (NN + SCAN_B - 1) / SCAN_B;
  int nbB = (NE + CHUNK - 1) / CHUNK;

  k_prep0<<<97, 256, 0, stream>>>(gcur, W1, WT1, W2, WT2);
  k_bucket<<<nbB, 256, 0, stream>>>(row, col, gcur, pr_row, pr_li);
  k_bdeg<<<NBUK, 256, 0, stream>>>(pr_li, gcur, deg, dinv);
  k_scan1<<<nbScan, SCAN_B, 0, stream>>>(deg, offs, bsums);
  k_scan2<<<1, 128, 0, stream>>>(bsums, nbScan);
  k_scan3<<<nbScan, SCAN_B, 0, stream>>>(offs, bsums);
  k_bfill<<<NBUK, 256, 0, stream>>>(pr_row, pr_li, gcur, offs, dinv, wcsr);

  int nbG = (NN + 63) / 64;
  int nbA = (NSEG + 3) / 4;
  k_gemm128<<<nbG, 256, 0, stream>>>(x, WT1, t);
  k_agg128<<<nbA, 256, 0, stream>>>(t, offs, wcsr, b1, h1);
  k_gemm64<<<nbG, 256, 0, stream>>>(h1, WT2, t);
  k_agg64<<<nbA, 256, 0, stream>>>(t, offs, wcsr, b2, out);
}

// Round 7
// 263.191 us; speedup vs baseline: 1.0233x; 1.0233x over previous
//
#include <hip/hip_runtime.h>

#define NN 100000
#define NE 1600000
#define SCAN_B 1024
#define NSEG 6250         // NN/16 target-node segments (one wave each)

// bucketed counting sort params: 512 nodes per bucket
#define BSH 9
#define BSZ 512
#define NBUK 196          // ceil(NN / BSZ)
#define CAP 12288         // per-bucket pair capacity (mean 8163, huge margin)
#define CHUNK 4096        // edges per block in k_bucket

typedef short bs8 __attribute__((ext_vector_type(8)));
typedef float f32x4 __attribute__((ext_vector_type(4)));
typedef unsigned long long u64;
#define MFMA16(a, b, c) __builtin_amdgcn_mfma_f32_16x16x32_bf16(a, b, c, 0, 0, 0)

static inline size_t alignup(size_t x) { return (x + 255) & ~(size_t)255; }

__device__ __forceinline__ ushort f2bf(float f) {  // RNE, finite inputs
  uint u = __float_as_uint(f);
  u += 0x7fffu + ((u >> 16) & 1u);
  return (ushort)(u >> 16);
}

// ds_read_b64_tr_b16: byte addr A -> reads column c=(A>>3)&15 of the 128B
// panel (A&~127): 4 bf16 elements at panel + c*2 + {0,32,64,96} bytes.
__device__ __forceinline__ u64 tr16(uint addr) {
  u64 d;
  asm volatile("ds_read_b64_tr_b16 %0, %1" : "=v"(d) : "v"(addr));
  return d;
}
__device__ __forceinline__ u64 tr16_128(uint addr) {
  u64 d;
  asm volatile("ds_read_b64_tr_b16 %0, %1 offset:128" : "=v"(d) : "v"(addr));
  return d;
}

union frag_u { struct { u64 a, b; } q; bs8 v; };

// ---------------- graph prep (bucketed counting sort) ----------------

__global__ __launch_bounds__(256) void k_prep0(int* __restrict__ gcur,
                                               const float* __restrict__ W1, ushort* __restrict__ WT1,
                                               const float* __restrict__ W2, ushort* __restrict__ WT2) {
  int b = blockIdx.x, t = threadIdx.x;
  if (b < 64) {  // W1: [128,128] -> WT1[c][k]
    int i = b * 256 + t;
    int k = i >> 7, c = i & 127;
    WT1[c * 128 + k] = f2bf(W1[i]);
  } else if (b < 96) {  // W2: [128,64] -> WT2[c][k]
    int i = (b - 64) * 256 + t;
    int k = i >> 6, c = i & 63;
    WT2[c * 128 + k] = f2bf(W2[i]);
  } else {
    if (t < NBUK) gcur[t] = t * CAP;
  }
}

__global__ __launch_bounds__(256) void k_bucket(const int* __restrict__ row, const int* __restrict__ col,
                                                int* __restrict__ gcur, uint* __restrict__ pr_row,
                                                ushort* __restrict__ pr_li) {
  __shared__ int cnt[NBUK];
  int t = threadIdx.x;
  for (int i = t; i < NBUK; i += 256) cnt[i] = 0;
  __syncthreads();
  int e0 = blockIdx.x * CHUNK;
  int e1 = min(e0 + CHUNK, NE);
  for (int e = e0 + t; e < e1; e += 256) atomicAdd(&cnt[col[e] >> BSH], 1);
  __syncthreads();
  for (int i = t; i < NBUK; i += 256) {
    int c = cnt[i];
    cnt[i] = c ? atomicAdd(&gcur[i], c) : 0;
  }
  __syncthreads();
  for (int e = e0 + t; e < e1; e += 256) {
    int c = col[e];
    int p = atomicAdd(&cnt[c >> BSH], 1);
    pr_row[p] = (uint)row[e];
    pr_li[p] = (ushort)(c & (BSZ - 1));
  }
}

// per-bucket degree count (+1 self loop) fused with dinv
__global__ __launch_bounds__(256) void k_bdeg(const ushort* __restrict__ pr_li, const int* __restrict__ gcur,
                                              int* __restrict__ deg, float* __restrict__ dinv) {
  __shared__ int dc[BSZ];
  int t = threadIdx.x, b = blockIdx.x;
  for (int i = t; i < BSZ; i += 256) dc[i] = 0;
  __syncthreads();
  int s = b * CAP;
  int n = min(gcur[b] - s, CAP);
  for (int i = t; i < n; i += 256) atomicAdd(&dc[pr_li[s + i]], 1);
  __syncthreads();
  int nb0 = b << BSH;
  for (int i = t; i < BSZ; i += 256) {
    int node = nb0 + i;
    if (node < NN) {
      int d = dc[i] + 1;
      deg[node] = d;
      dinv[node] = rsqrtf((float)d);
    }
  }
}

// exclusive scan of deg (WITH self-loops) -> offs; CSR holds NE+NN entries
__global__ __launch_bounds__(SCAN_B) void k_scan1(const int* __restrict__ deg, int* __restrict__ offs,
                                                  int* __restrict__ bsums) {
  __shared__ int sm[SCAN_B];
  int i = blockIdx.x * SCAN_B + threadIdx.x;
  int v = (i < NN) ? deg[i] : 0;
  sm[threadIdx.x] = v;
  __syncthreads();
  for (int d = 1; d < SCAN_B; d <<= 1) {
    int t = (threadIdx.x >= d) ? sm[threadIdx.x - d] : 0;
    __syncthreads();
    sm[threadIdx.x] += t;
    __syncthreads();
  }
  if (i < NN) offs[i] = sm[threadIdx.x] - v;
  if (threadIdx.x == SCAN_B - 1) bsums[blockIdx.x] = sm[threadIdx.x];
}

__global__ __launch_bounds__(128) void k_scan2(int* __restrict__ bsums, int nb) {
  __shared__ int sm[128];
  int v = (threadIdx.x < nb) ? bsums[threadIdx.x] : 0;
  sm[threadIdx.x] = v;
  __syncthreads();
  for (int d = 1; d < 128; d <<= 1) {
    int t = (threadIdx.x >= d) ? sm[threadIdx.x - d] : 0;
    __syncthreads();
    sm[threadIdx.x] += t;
    __syncthreads();
  }
  if (threadIdx.x < nb) bsums[threadIdx.x] = sm[threadIdx.x] - v;
}

__global__ __launch_bounds__(SCAN_B) void k_scan3(int* __restrict__ offs, const int* __restrict__ bsums) {
  int i = blockIdx.x * SCAN_B + threadIdx.x;
  if (i < NN) offs[i] += bsums[blockIdx.x];
}

// weighted CSR incl. self-loops: entry = (src_row, bf16(w)<<16 | local_target&15)
__global__ __launch_bounds__(256) void k_bfill(const uint* __restrict__ pr_row, const ushort* __restrict__ pr_li,
                                               const int* __restrict__ gcur, const int* __restrict__ offs,
                                               const float* __restrict__ dinv, uint2* __restrict__ wcsr) {
  __shared__ int loff[BSZ];
  __shared__ int cur[BSZ];
  __shared__ float dl[BSZ];
  int t = threadIdx.x, b = blockIdx.x;
  int nb0 = b << BSH;
  for (int i = t; i < BSZ; i += 256) {
    int node = nb0 + i;
    if (node < NN) {
      int o = offs[node];
      float d = dinv[node];
      loff[i] = o;
      dl[i] = d;
      cur[i] = 1;  // slot 0 = self loop
      wcsr[o] = make_uint2((uint)node, ((uint)f2bf(d * d) << 16) | (uint)(i & 15));
    } else {
      loff[i] = 0; dl[i] = 0.f; cur[i] = 1;
    }
  }
  __syncthreads();
  int s = b * CAP;
  int n = min(gcur[b] - s, CAP);
  for (int i = t; i < n; i += 256) {
    int li = pr_li[s + i];
    uint r = pr_row[s + i];
    int p = atomicAdd(&cur[li], 1);
    wcsr[loff[li] + p] = make_uint2(r, ((uint)f2bf(dinv[r] * dl[li]) << 16) | (uint)(li & 15));
  }
}

// ---------------- dense transforms (bf16 MFMA) ----------------

__global__ __launch_bounds__(256) void k_gemm128(const float* __restrict__ x, const ushort* __restrict__ WT,
                                                 ushort* __restrict__ t) {
  int wave = threadIdx.x >> 6, lane = threadIdx.x & 63;
  int col0 = wave * 32;
  int lr = lane & 15;
  int lk = (lane >> 4) * 8;
  bs8 bfrag[2][4];
#pragma unroll
  for (int n = 0; n < 2; n++)
#pragma unroll
    for (int ks = 0; ks < 4; ks++)
      bfrag[n][ks] = *(const bs8*)&WT[(size_t)(col0 + n * 16 + lr) * 128 + ks * 32 + lk];
  int row0 = blockIdx.x * 64;
#pragma unroll 1
  for (int mt = 0; mt < 4; mt++) {
    int r0 = row0 + mt * 16;
    if (r0 >= NN) return;
    const float* xr = x + (size_t)(r0 + lr) * 128 + lk;
    f32x4 acc[2] = {{0.f, 0.f, 0.f, 0.f}, {0.f, 0.f, 0.f, 0.f}};
#pragma unroll
    for (int ks = 0; ks < 4; ks++) {
      float4 a0 = *(const float4*)&xr[ks * 32];
      float4 a1 = *(const float4*)&xr[ks * 32 + 4];
      bs8 af;
      af[0] = (short)f2bf(a0.x); af[1] = (short)f2bf(a0.y);
      af[2] = (short)f2bf(a0.z); af[3] = (short)f2bf(a0.w);
      af[4] = (short)f2bf(a1.x); af[5] = (short)f2bf(a1.y);
      af[6] = (short)f2bf(a1.z); af[7] = (short)f2bf(a1.w);
      acc[0] = MFMA16(af, bfrag[0][ks], acc[0]);
      acc[1] = MFMA16(af, bfrag[1][ks], acc[1]);
    }
    int rbase = r0 + (lane >> 4) * 4;
#pragma unroll
    for (int n = 0; n < 2; n++)
#pragma unroll
      for (int r = 0; r < 4; r++)
        t[(size_t)(rbase + r) * 128 + col0 + n * 16 + lr] = f2bf(acc[n][r]);
  }
}

__global__ __launch_bounds__(256) void k_gemm64(const ushort* __restrict__ h, const ushort* __restrict__ WT,
                                                ushort* __restrict__ t2) {
  int wave = threadIdx.x >> 6, lane = threadIdx.x & 63;
  int col0 = wave * 16;
  int lr = lane & 15;
  int lk = (lane >> 4) * 8;
  bs8 bfrag[4];
#pragma unroll
  for (int ks = 0; ks < 4; ks++)
    bfrag[ks] = *(const bs8*)&WT[(size_t)(col0 + lr) * 128 + ks * 32 + lk];
  int row0 = blockIdx.x * 64;
#pragma unroll 1
  for (int mt = 0; mt < 4; mt++) {
    int r0 = row0 + mt * 16;
    if (r0 >= NN) return;
    const ushort* hr = h + (size_t)(r0 + lr) * 128 + lk;
    f32x4 acc = {0.f, 0.f, 0.f, 0.f};
#pragma unroll
    for (int ks = 0; ks < 4; ks++) {
      bs8 af = *(const bs8*)&hr[ks * 32];
      acc = MFMA16(af, bfrag[ks], acc);
    }
    int rbase = r0 + (lane >> 4) * 4;
#pragma unroll
    for (int r = 0; r < 4; r++)
      t2[(size_t)(rbase + r) * 64 + col0 + lr] = f2bf(acc[r]);
  }
}

// ---------------- MFMA segment aggregation (wide gather + LDS transpose) ----------------
// One wave owns 16 target nodes. Per 32-slot batch: stage 32 gathered rows in
// 8x[32k][16n] LDS tiles (vectorized), read B-frags via ds_read_b64_tr_b16,
// A = one-hot weights from a 4xuint4 wcsr window (no shuffles).

__global__ __launch_bounds__(256) void k_agg128(const ushort* __restrict__ t, const int* __restrict__ offs,
                                                const uint2* __restrict__ wcsr, const float* __restrict__ bias,
                                                ushort* __restrict__ out) {
  __shared__ __align__(128) ushort L[4 * 4096];  // 4 waves x 8 tiles x [32][16]
  int wave = threadIdx.x >> 6, lane = threadIdx.x & 63;
  int seg = blockIdx.x * 4 + wave;
  if (seg >= NSEG) return;
  int seg0 = seg * 16;
  int e0 = offs[seg0];
  int e1 = (seg0 + 16 == NN) ? (NE + NN) : offs[seg0 + 16];
  int g = lane >> 4, f = lane & 15;
  int fl = f & 7, half = f >> 3;
  int s = g * 8 + fl;                 // this lane's gather slot (within batch)
  int wb = wave * 4096;               // elem offset of wave's LDS region
  uint Lb = (uint)(size_t)&L[wb];     // LDS byte address (low 32 bits = offset)
  const char* tb = (const char*)t;

  f32x4 acc[8];
#pragma unroll
  for (int i = 0; i < 8; i++) acc[i] = (f32x4){0.f, 0.f, 0.f, 0.f};

  int nb = (e1 - e0 + 31) >> 5;
#pragma unroll 1
  for (int b = 0; b < nb; b++) {
    int base = e0 + b * 32;
    int wi = base + g * 8;
    uint4 W0 = *(const uint4*)(wcsr + wi);
    uint4 W1 = *(const uint4*)(wcsr + wi + 2);
    uint4 W2 = *(const uint4*)(wcsr + wi + 4);
    uint4 W3 = *(const uint4*)(wcsr + wi + 6);
    // own gather row = ex of slot fl within the window
    uint ex0 = (fl & 1) ? W0.z : W0.x;
    uint ex1 = (fl & 1) ? W1.z : W1.x;
    uint ex2 = (fl & 1) ? W2.z : W2.x;
    uint ex3 = (fl & 1) ? W3.z : W3.x;
    uint exl = (fl & 4) ? ((fl & 2) ? ex3 : ex2) : ((fl & 2) ? ex1 : ex0);
    if (base + s >= e1) exl = 0;  // dummy row; masked via af
    const uint4* src = (const uint4*)(tb + ((size_t)exl << 8) + (size_t)(half * 128));
    uint4 G[8];
#pragma unroll
    for (int i = 0; i < 8; i++) G[i] = src[i];
    // A-frag: af[j] = w_j if slot (g*8+j) targets local node f, else 0
    bs8 af;
#pragma unroll
    for (int j = 0; j < 8; j++) {
      uint ey;
      switch (j >> 1) {
        case 0: ey = (j & 1) ? W0.w : W0.y; break;
        case 1: ey = (j & 1) ? W1.w : W1.y; break;
        case 2: ey = (j & 1) ? W2.w : W2.y; break;
        default: ey = (j & 1) ? W3.w : W3.y; break;
      }
      bool ok = (base + g * 8 + j < e1) && ((ey & 15u) == (uint)f);
      af[j] = ok ? (short)(ushort)(ey >> 16) : (short)0;
    }
    // stage rows: tile = half*4 + i/2, row = s, cols (i&1)*8..+7
#pragma unroll
    for (int i = 0; i < 8; i++)
      *(uint4*)&L[wb + (half * 4 + (i >> 1)) * 512 + s * 16 + (i & 1) * 8] = G[i];
    asm volatile("s_waitcnt lgkmcnt(0)" ::: "memory");
    __builtin_amdgcn_sched_barrier(0);
    // tr16 column addressing: column f -> byte offset f*8 within panel
    frag_u U[2];
    uint a0 = Lb + (uint)(g * 256 + f * 8);
    U[0].q.a = tr16(a0);
    U[0].q.b = tr16_128(a0);
#pragma unroll
    for (int ft = 0; ft < 8; ft++) {
      if (ft < 7) {
        uint an = a0 + (uint)((ft + 1) * 1024);
        U[(ft + 1) & 1].q.a = tr16(an);
        U[(ft + 1) & 1].q.b = tr16_128(an);
        asm volatile("s_waitcnt lgkmcnt(2)" ::: "memory");
      } else {
        asm volatile("s_waitcnt lgkmcnt(0)" ::: "memory");
      }
      __builtin_amdgcn_sched_barrier(0);
      acc[ft] = MFMA16(af, U[ft & 1].v, acc[ft]);
    }
  }
  // C layout: col=f, row=g*4+reg ; add bias, relu, store bf16
#pragma unroll
  for (int ft = 0; ft < 8; ft++) {
    float bb = bias[ft * 16 + f];
#pragma unroll
    for (int r = 0; r < 4; r++) {
      int node = seg0 + g * 4 + r;
      out[(size_t)node * 128 + ft * 16 + f] = f2bf(fmaxf(acc[ft][r] + bb, 0.f));
    }
  }
}

__global__ __launch_bounds__(256) void k_agg64(const ushort* __restrict__ t, const int* __restrict__ offs,
                                               const uint2* __restrict__ wcsr, const float* __restrict__ bias,
                                               float* __restrict__ out) {
  __shared__ __align__(128) ushort L[4 * 2048];  // 4 waves x 4 tiles x [32][16]
  int wave = threadIdx.x >> 6, lane = threadIdx.x & 63;
  int seg = blockIdx.x * 4 + wave;
  if (seg >= NSEG) return;
  int seg0 = seg * 16;
  int e0 = offs[seg0];
  int e1 = (seg0 + 16 == NN) ? (NE + NN) : offs[seg0 + 16];
  int g = lane >> 4, f = lane & 15;
  int fl = f & 7, half = f >> 3;
  int s = g * 8 + fl;
  int wb = wave * 2048;
  uint Lb = (uint)(size_t)&L[wb];
  const char* tb = (const char*)t;

  f32x4 acc[4];
#pragma unroll
  for (int i = 0; i < 4; i++) acc[i] = (f32x4){0.f, 0.f, 0.f, 0.f};

  int nb = (e1 - e0 + 31) >> 5;
#pragma unroll 1
  for (int b = 0; b < nb; b++) {
    int base = e0 + b * 32;
    int wi = base + g * 8;
    uint4 W0 = *(const uint4*)(wcsr + wi);
    uint4 W1 = *(const uint4*)(wcsr + wi + 2);
    uint4 W2 = *(const uint4*)(wcsr + wi + 4);
    uint4 W3 = *(const uint4*)(wcsr + wi + 6);
    uint ex0 = (fl & 1) ? W0.z : W0.x;
    uint ex1 = (fl & 1) ? W1.z : W1.x;
    uint ex2 = (fl & 1) ? W2.z : W2.x;
    uint ex3 = (fl & 1) ? W3.z : W3.x;
    uint exl = (fl & 4) ? ((fl & 2) ? ex3 : ex2) : ((fl & 2) ? ex1 : ex0);
    if (base + s >= e1) exl = 0;
    const uint4* src = (const uint4*)(tb + ((size_t)exl << 7) + (size_t)(half * 64));
    uint4 G[4];
#pragma unroll
    for (int i = 0; i < 4; i++) G[i] = src[i];
    bs8 af;
#pragma unroll
    for (int j = 0; j < 8; j++) {
      uint ey;
      switch (j >> 1) {
        case 0: ey = (j & 1) ? W0.w : W0.y; break;
        case 1: ey = (j & 1) ? W1.w : W1.y; break;
        case 2: ey = (j & 1) ? W2.w : W2.y; break;
        default: ey = (j & 1) ? W3.w : W3.y; break;
      }
      bool ok = (base + g * 8 + j < e1) && ((ey & 15u) == (uint)f);
      af[j] = ok ? (short)(ushort)(ey >> 16) : (short)0;
    }
#pragma unroll
    for (int i = 0; i < 4; i++)
      *(uint4*)&L[wb + (half * 2 + (i >> 1)) * 512 + s * 16 + (i & 1) * 8] = G[i];
    asm volatile("s_waitcnt lgkmcnt(0)" ::: "memory");
    __builtin_amdgcn_sched_barrier(0);
    frag_u U[2];
    uint a0 = Lb + (uint)(g * 256 + f * 8);
    U[0].q.a = tr16(a0);
    U[0].q.b = tr16_128(a0);
#pragma unroll
    for (int ft = 0; ft < 4; ft++) {
      if (ft < 3) {
        uint an = a0 + (uint)((ft + 1) * 1024);
        U[(ft + 1) & 1].q.a = tr16(an);
        U[(ft + 1) & 1].q.b = tr16_128(an);
        asm volatile("s_waitcnt lgkmcnt(2)" ::: "memory");
      } else {
        asm volatile("s_waitcnt lgkmcnt(0)" ::: "memory");
      }
      __builtin_amdgcn_sched_barrier(0);
      acc[ft] = MFMA16(af, U[ft & 1].v, acc[ft]);
    }
  }
#pragma unroll
  for (int ft = 0; ft < 4; ft++) {
    float bb = bias[ft * 16 + f];
#pragma unroll
    for (int r = 0; r < 4; r++) {
      int node = seg0 + g * 4 + r;
      out[(size_t)node * 64 + ft * 16 + f] = acc[ft][r] + bb;
    }
  }
}

// ---------------- host ----------------

extern "C" void kernel_launch(void* const* d_in, const int* in_sizes, int n_in,
                              void* d_out, int out_size, void* d_ws, size_t ws_size,
                              hipStream_t stream) {
  const float* x  = (const float*)d_in[0];
  const int*   ei = (const int*)d_in[1];
  const float* W1 = (const float*)d_in[2];
  const float* b1 = (const float*)d_in[3];
  const float* W2 = (const float*)d_in[4];
  const float* b2 = (const float*)d_in[5];
  float* out = (float*)d_out;

  char* p = (char*)d_ws;
  int* deg      = (int*)p;    p += alignup((size_t)NN * 4);
  int* gcur     = (int*)p;    p += alignup((size_t)NBUK * 4);
  int* offs     = (int*)p;    p += alignup((size_t)NN * 4);
  int* bsums    = (int*)p;    p += alignup(128 * 4);
  float* dinv   = (float*)p;  p += alignup((size_t)NN * 4);
  uint2* wcsr   = (uint2*)p;  p += alignup((size_t)(NE + NN + 64) * 8);  // +64 pad for window overread
  ushort* WT1   = (ushort*)p; p += alignup(128 * 128 * 2);
  ushort* WT2   = (ushort*)p; p += alignup(64 * 128 * 2);
  ushort* t     = (ushort*)p; p += alignup((size_t)NN * 128 * 2);  // reused for t2
  ushort* h1    = (ushort*)p; p += alignup((size_t)NN * 128 * 2);
  // pair buffers alias t (dead before k_gemm128 writes t)
  uint* pr_row  = (uint*)t;
  ushort* pr_li = (ushort*)((char*)t + alignup((size_t)NBUK * CAP * 4));
  (void)ws_size; (void)in_sizes; (void)n_in; (void)out_size;

  const int* row = ei;
  const int* col = ei + NE;

  int nbScan = (NN + SCAN_B - 1) / SCAN_B;
  int nbB = (NE + CHUNK - 1) / CHUNK;

  k_prep0<<<97, 256, 0, stream>>>(gcur, W1, WT1, W2, WT2);
  k_bucket<<<nbB, 256, 0, stream>>>(row, col, gcur, pr_row, pr_li);
  k_bdeg<<<NBUK, 256, 0, stream>>>(pr_li, gcur, deg, dinv);
  k_scan1<<<nbScan, SCAN_B, 0, stream>>>(deg, offs, bsums);
  k_scan2<<<1, 128, 0, stream>>>(bsums, nbScan);
  k_scan3<<<nbScan, SCAN_B, 0, stream>>>(offs, bsums);
  k_bfill<<<NBUK, 256, 0, stream>>>(pr_row, pr_li, gcur, offs, dinv, wcsr);

  int nbG = (NN + 63) / 64;
  int nbA = (NSEG + 3) / 4;
  k_gemm128<<<nbG, 256, 0, stream>>>(x, WT1, t);
  k_agg128<<<nbA, 256, 0, stream>>>(t, offs, wcsr, b1, h1);
  k_gemm64<<<nbG, 256, 0, stream>>>(h1, WT2, t);
  k_agg64<<<nbA, 256, 0, stream>>>(t, offs, wcsr, b2, out);
}

// Round 8
// 232.795 us; speedup vs baseline: 1.1569x; 1.1306x over previous
//
#include <hip/hip_runtime.h>

#define NN 100000
#define NE 1600000
#define SCAN_B 1024

// bucketed counting sort params: 512 nodes per bucket
#define BSH 9
#define BSZ 512
#define NBUK 196          // ceil(NN / BSZ)
#define CAP 12288         // per-bucket pair capacity (mean 8163, huge margin)
#define CHUNK 4096        // edges per block in k_bucket

typedef _Float16 hs8 __attribute__((ext_vector_type(8)));
typedef float f32x4 __attribute__((ext_vector_type(4)));
#define MFMA16H(a, b, c) __builtin_amdgcn_mfma_f32_16x16x32_f16(a, b, c, 0, 0, 0)

static inline size_t alignup(size_t x) { return (x + 255) & ~(size_t)255; }

union h8u { uint4 q; _Float16 h[8]; };

// ---------------- graph prep (bucketed counting sort) ----------------

// fused: gcur init + W1/W2 fp32->fp16 transposed converts
__global__ __launch_bounds__(256) void k_prep0(int* __restrict__ gcur,
                                               const float* __restrict__ W1, _Float16* __restrict__ WT1,
                                               const float* __restrict__ W2, _Float16* __restrict__ WT2) {
  int b = blockIdx.x, t = threadIdx.x;
  if (b < 64) {  // W1: [128,128] -> WT1[c][k]
    int i = b * 256 + t;
    int k = i >> 7, c = i & 127;
    WT1[c * 128 + k] = (_Float16)W1[i];
  } else if (b < 96) {  // W2: [128,64] -> WT2[c][k]
    int i = (b - 64) * 256 + t;
    int k = i >> 6, c = i & 63;
    WT2[c * 128 + k] = (_Float16)W2[i];
  } else {
    if (t < NBUK) gcur[t] = t * CAP;
  }
}

// bin edges into buckets; packed pair = (row<<9) | local_index
__global__ __launch_bounds__(256) void k_bucket(const int* __restrict__ row, const int* __restrict__ col,
                                                int* __restrict__ gcur, uint* __restrict__ pr_pack) {
  __shared__ int cnt[NBUK];
  int t = threadIdx.x;
  for (int i = t; i < NBUK; i += 256) cnt[i] = 0;
  __syncthreads();
  int e0 = blockIdx.x * CHUNK;
  int e1 = min(e0 + CHUNK, NE);
  for (int e = e0 + t; e < e1; e += 256) atomicAdd(&cnt[col[e] >> BSH], 1);
  __syncthreads();
  for (int i = t; i < NBUK; i += 256) {
    int c = cnt[i];
    cnt[i] = c ? atomicAdd(&gcur[i], c) : 0;
  }
  __syncthreads();
  for (int e = e0 + t; e < e1; e += 256) {
    int c = col[e];
    int p = atomicAdd(&cnt[c >> BSH], 1);
    pr_pack[p] = ((uint)row[e] << BSH) | (uint)(c & (BSZ - 1));
  }
}

// per-bucket degree count (+1 self loop) fused with dinv
__global__ __launch_bounds__(256) void k_bdeg(const uint* __restrict__ pr_pack, const int* __restrict__ gcur,
                                              int* __restrict__ deg, float* __restrict__ dinv) {
  __shared__ int dc[BSZ];
  int t = threadIdx.x, b = blockIdx.x;
  for (int i = t; i < BSZ; i += 256) dc[i] = 0;
  __syncthreads();
  int s = b * CAP;
  int n = min(gcur[b] - s, CAP);
  for (int i = t; i < n; i += 256) atomicAdd(&dc[pr_pack[s + i] & (BSZ - 1)], 1);
  __syncthreads();
  int nb0 = b << BSH;
  for (int i = t; i < BSZ; i += 256) {
    int node = nb0 + i;
    if (node < NN) {
      int d = dc[i] + 1;
      deg[node] = d;
      dinv[node] = rsqrtf((float)d);
    }
  }
}

// exclusive scan of deg (WITH self-loops) -> offs; CSR holds NE+NN entries
__global__ __launch_bounds__(SCAN_B) void k_scan1(const int* __restrict__ deg, int* __restrict__ offs,
                                                  int* __restrict__ bsums) {
  __shared__ int sm[SCAN_B];
  int i = blockIdx.x * SCAN_B + threadIdx.x;
  int v = (i < NN) ? deg[i] : 0;
  sm[threadIdx.x] = v;
  __syncthreads();
  for (int d = 1; d < SCAN_B; d <<= 1) {
    int t = (threadIdx.x >= d) ? sm[threadIdx.x - d] : 0;
    __syncthreads();
    sm[threadIdx.x] += t;
    __syncthreads();
  }
  if (i < NN) offs[i] = sm[threadIdx.x] - v;
  if (threadIdx.x == SCAN_B - 1) bsums[blockIdx.x] = sm[threadIdx.x];
}

__global__ __launch_bounds__(128) void k_scan2(int* __restrict__ bsums, int nb) {
  __shared__ int sm[128];
  int v = (threadIdx.x < nb) ? bsums[threadIdx.x] : 0;
  sm[threadIdx.x] = v;
  __syncthreads();
  for (int d = 1; d < 128; d <<= 1) {
    int t = (threadIdx.x >= d) ? sm[threadIdx.x - d] : 0;
    __syncthreads();
    sm[threadIdx.x] += t;
    __syncthreads();
  }
  if (threadIdx.x < nb) bsums[threadIdx.x] = sm[threadIdx.x] - v;
}

__global__ __launch_bounds__(SCAN_B) void k_scan3(int* __restrict__ offs, const int* __restrict__ bsums) {
  int i = blockIdx.x * SCAN_B + threadIdx.x;
  if (i < NN) offs[i] += bsums[blockIdx.x];
}

// weighted CSR incl. self-loops: entry = (src_row, fp32 weight)
__global__ __launch_bounds__(256) void k_bfill(const uint* __restrict__ pr_pack, const int* __restrict__ gcur,
                                               const int* __restrict__ offs, const float* __restrict__ dinv,
                                               uint2* __restrict__ wcsr) {
  __shared__ int loff[BSZ];
  __shared__ int cur[BSZ];
  __shared__ float dl[BSZ];
  int t = threadIdx.x, b = blockIdx.x;
  int nb0 = b << BSH;
  for (int i = t; i < BSZ; i += 256) {
    int node = nb0 + i;
    if (node < NN) {
      int o = offs[node];
      float d = dinv[node];
      loff[i] = o;
      dl[i] = d;
      cur[i] = 1;  // slot 0 = self loop
      wcsr[o] = make_uint2((uint)node, __float_as_uint(d * d));
    } else {
      loff[i] = 0; dl[i] = 0.f; cur[i] = 1;
    }
  }
  __syncthreads();
  int s = b * CAP;
  int n = min(gcur[b] - s, CAP);
  for (int i = t; i < n; i += 256) {
    uint prk = pr_pack[s + i];
    int li = (int)(prk & (BSZ - 1));
    uint r = prk >> BSH;
    int p = atomicAdd(&cur[li], 1);
    wcsr[loff[li] + p] = make_uint2(r, __float_as_uint(dinv[r] * dl[li]));
  }
}

// ---------------- dense transforms (fp16 MFMA) ----------------

__global__ __launch_bounds__(256) void k_gemm128(const float* __restrict__ x, const _Float16* __restrict__ WT,
                                                 _Float16* __restrict__ t) {
  int wave = threadIdx.x >> 6, lane = threadIdx.x & 63;
  int col0 = wave * 32;
  int lr = lane & 15;
  int lk = (lane >> 4) * 8;
  hs8 bfrag[2][4];
#pragma unroll
  for (int n = 0; n < 2; n++)
#pragma unroll
    for (int ks = 0; ks < 4; ks++)
      bfrag[n][ks] = *(const hs8*)&WT[(size_t)(col0 + n * 16 + lr) * 128 + ks * 32 + lk];
  int row0 = blockIdx.x * 64;
#pragma unroll 1
  for (int mt = 0; mt < 4; mt++) {
    int r0 = row0 + mt * 16;
    if (r0 >= NN) return;
    const float* xr = x + (size_t)(r0 + lr) * 128 + lk;
    f32x4 acc[2] = {{0.f, 0.f, 0.f, 0.f}, {0.f, 0.f, 0.f, 0.f}};
#pragma unroll
    for (int ks = 0; ks < 4; ks++) {
      float4 a0 = *(const float4*)&xr[ks * 32];
      float4 a1 = *(const float4*)&xr[ks * 32 + 4];
      hs8 af;
      af[0] = (_Float16)a0.x; af[1] = (_Float16)a0.y;
      af[2] = (_Float16)a0.z; af[3] = (_Float16)a0.w;
      af[4] = (_Float16)a1.x; af[5] = (_Float16)a1.y;
      af[6] = (_Float16)a1.z; af[7] = (_Float16)a1.w;
      acc[0] = MFMA16H(af, bfrag[0][ks], acc[0]);
      acc[1] = MFMA16H(af, bfrag[1][ks], acc[1]);
    }
    int rbase = r0 + (lane >> 4) * 4;
#pragma unroll
    for (int n = 0; n < 2; n++)
#pragma unroll
      for (int r = 0; r < 4; r++)
        t[(size_t)(rbase + r) * 128 + col0 + n * 16 + lr] = (_Float16)acc[n][r];
  }
}

__global__ __launch_bounds__(256) void k_gemm64(const _Float16* __restrict__ h, const _Float16* __restrict__ WT,
                                                _Float16* __restrict__ t2) {
  int wave = threadIdx.x >> 6, lane = threadIdx.x & 63;
  int col0 = wave * 16;
  int lr = lane & 15;
  int lk = (lane >> 4) * 8;
  hs8 bfrag[4];
#pragma unroll
  for (int ks = 0; ks < 4; ks++)
    bfrag[ks] = *(const hs8*)&WT[(size_t)(col0 + lr) * 128 + ks * 32 + lk];
  int row0 = blockIdx.x * 64;
#pragma unroll 1
  for (int mt = 0; mt < 4; mt++) {
    int r0 = row0 + mt * 16;
    if (r0 >= NN) return;
    const _Float16* hr = h + (size_t)(r0 + lr) * 128 + lk;
    f32x4 acc = {0.f, 0.f, 0.f, 0.f};
#pragma unroll
    for (int ks = 0; ks < 4; ks++) {
      hs8 af = *(const hs8*)&hr[ks * 32];
      acc = MFMA16H(af, bfrag[ks], acc);
    }
    int rbase = r0 + (lane >> 4) * 4;
#pragma unroll
    for (int r = 0; r < 4; r++)
      t2[(size_t)(rbase + r) * 64 + col0 + lr] = (_Float16)acc[r];
  }
}

// ---------------- aggregation (grouped-lane wide gathers, fp32 accum via fma_mix) ----------------

// 4 groups of 16 lanes; group g handles edge 4k+g; lane loads 16B (8 fp16 feats)
__global__ __launch_bounds__(256) void k_agg128(const _Float16* __restrict__ t, const int* __restrict__ offs,
                                                const int* __restrict__ deg, const uint2* __restrict__ wcsr,
                                                const float* __restrict__ bias, _Float16* __restrict__ out) {
  int wave = threadIdx.x >> 6, lane = threadIdx.x & 63;
  int node = blockIdx.x * 4 + wave;
  if (node >= NN) return;
  int g = lane >> 4, f = lane & 15;
  float acc[8] = {};
  int beg = offs[node];
  int cnt = deg[node];  // includes self-loop slot
  const char* tb = (const char*)t;
  for (int base = 0; base < cnt; base += 64) {
    int m = min(64, cnt - base);
    uint2 pr = (lane < m) ? wcsr[beg + base + lane] : make_uint2(0u, 0u);
    int ridx = (int)pr.x;
    float wv = __uint_as_float(pr.y);
    int mm = (m + 3) >> 2;
    for (int k = 0; k < mm; k++) {
      int src = k * 4 + g;
      int r = __shfl(ridx, src);
      float s = __shfl(wv, src);  // 0 for padded slots
      h8u u;
      u.q = *(const uint4*)(tb + (((size_t)(uint)r) << 8) + (f << 4));
      acc[0] = fmaf((float)u.h[0], s, acc[0]);
      acc[1] = fmaf((float)u.h[1], s, acc[1]);
      acc[2] = fmaf((float)u.h[2], s, acc[2]);
      acc[3] = fmaf((float)u.h[3], s, acc[3]);
      acc[4] = fmaf((float)u.h[4], s, acc[4]);
      acc[5] = fmaf((float)u.h[5], s, acc[5]);
      acc[6] = fmaf((float)u.h[6], s, acc[6]);
      acc[7] = fmaf((float)u.h[7], s, acc[7]);
    }
  }
#pragma unroll
  for (int j = 0; j < 8; j++) {
    acc[j] += __shfl_xor(acc[j], 16);
    acc[j] += __shfl_xor(acc[j], 32);
  }
  if (g == 0) {
    float4 b0 = *(const float4*)&bias[f * 8];
    float4 b1 = *(const float4*)&bias[f * 8 + 4];
    h8u st;
    st.h[0] = (_Float16)fmaxf(acc[0] + b0.x, 0.f);
    st.h[1] = (_Float16)fmaxf(acc[1] + b0.y, 0.f);
    st.h[2] = (_Float16)fmaxf(acc[2] + b0.z, 0.f);
    st.h[3] = (_Float16)fmaxf(acc[3] + b0.w, 0.f);
    st.h[4] = (_Float16)fmaxf(acc[4] + b1.x, 0.f);
    st.h[5] = (_Float16)fmaxf(acc[5] + b1.y, 0.f);
    st.h[6] = (_Float16)fmaxf(acc[6] + b1.z, 0.f);
    st.h[7] = (_Float16)fmaxf(acc[7] + b1.w, 0.f);
    *(uint4*)&out[(size_t)node * 128 + f * 8] = st.q;
  }
}

// 8 groups of 8 lanes; group g handles edge 8k+g; lane loads 16B (8 fp16 feats)
__global__ __launch_bounds__(256) void k_agg64(const _Float16* __restrict__ t, const int* __restrict__ offs,
                                               const int* __restrict__ deg, const uint2* __restrict__ wcsr,
                                               const float* __restrict__ bias, float* __restrict__ out) {
  int wave = threadIdx.x >> 6, lane = threadIdx.x & 63;
  int node = blockIdx.x * 4 + wave;
  if (node >= NN) return;
  int g = lane >> 3, fl = lane & 7;
  float acc[8] = {};
  int beg = offs[node];
  int cnt = deg[node];
  const char* tb = (const char*)t;
  for (int base = 0; base < cnt; base += 64) {
    int m = min(64, cnt - base);
    uint2 pr = (lane < m) ? wcsr[beg + base + lane] : make_uint2(0u, 0u);
    int ridx = (int)pr.x;
    float wv = __uint_as_float(pr.y);
    int mm = (m + 7) >> 3;
    for (int k = 0; k < mm; k++) {
      int src = k * 8 + g;
      int r = __shfl(ridx, src);
      float s = __shfl(wv, src);
      h8u u;
      u.q = *(const uint4*)(tb + (((size_t)(uint)r) << 7) + (fl << 4));
      acc[0] = fmaf((float)u.h[0], s, acc[0]);
      acc[1] = fmaf((float)u.h[1], s, acc[1]);
      acc[2] = fmaf((float)u.h[2], s, acc[2]);
      acc[3] = fmaf((float)u.h[3], s, acc[3]);
      acc[4] = fmaf((float)u.h[4], s, acc[4]);
      acc[5] = fmaf((float)u.h[5], s, acc[5]);
      acc[6] = fmaf((float)u.h[6], s, acc[6]);
      acc[7] = fmaf((float)u.h[7], s, acc[7]);
    }
  }
#pragma unroll
  for (int j = 0; j < 8; j++) {
    acc[j] += __shfl_xor(acc[j], 8);
    acc[j] += __shfl_xor(acc[j], 16);
    acc[j] += __shfl_xor(acc[j], 32);
  }
  if (g == 0) {
    float4 b0 = *(const float4*)&bias[fl * 8];
    float4 b1 = *(const float4*)&bias[fl * 8 + 4];
    float4 o0 = make_float4(acc[0] + b0.x, acc[1] + b0.y, acc[2] + b0.z, acc[3] + b0.w);
    float4 o1 = make_float4(acc[4] + b1.x, acc[5] + b1.y, acc[6] + b1.z, acc[7] + b1.w);
    *(float4*)&out[(size_t)node * 64 + fl * 8] = o0;
    *(float4*)&out[(size_t)node * 64 + fl * 8 + 4] = o1;
  }
}

// ---------------- host ----------------

extern "C" void kernel_launch(void* const* d_in, const int* in_sizes, int n_in,
                              void* d_out, int out_size, void* d_ws, size_t ws_size,
                              hipStream_t stream) {
  const float* x  = (const float*)d_in[0];
  const int*   ei = (const int*)d_in[1];
  const float* W1 = (const float*)d_in[2];
  const float* b1 = (const float*)d_in[3];
  const float* W2 = (const float*)d_in[4];
  const float* b2 = (const float*)d_in[5];
  float* out = (float*)d_out;

  char* p = (char*)d_ws;
  int* deg       = (int*)p;      p += alignup((size_t)NN * 4);
  int* gcur      = (int*)p;      p += alignup((size_t)NBUK * 4);
  int* offs      = (int*)p;      p += alignup((size_t)NN * 4);
  int* bsums     = (int*)p;      p += alignup(128 * 4);
  float* dinv    = (float*)p;    p += alignup((size_t)NN * 4);
  uint2* wcsr    = (uint2*)p;    p += alignup((size_t)(NE + NN + 64) * 8);
  _Float16* WT1  = (_Float16*)p; p += alignup(128 * 128 * 2);
  _Float16* WT2  = (_Float16*)p; p += alignup(64 * 128 * 2);
  _Float16* t    = (_Float16*)p; p += alignup((size_t)NN * 128 * 2);  // reused for t2
  _Float16* h1   = (_Float16*)p; p += alignup((size_t)NN * 128 * 2);
  // packed pair buffer aliases t (dead before k_gemm128 writes t)
  uint* pr_pack  = (uint*)t;
  (void)ws_size; (void)in_sizes; (void)n_in; (void)out_size;

  const int* row = ei;
  const int* col = ei + NE;

  int nbScan = (NN + SCAN_B - 1) / SCAN_B;
  int nbB = (NE + CHUNK - 1) / CHUNK;

  k_prep0<<<97, 256, 0, stream>>>(gcur, W1, WT1, W2, WT2);
  k_bucket<<<nbB, 256, 0, stream>>>(row, col, gcur, pr_pack);
  k_bdeg<<<NBUK, 256, 0, stream>>>(pr_pack, gcur, deg, dinv);
  k_scan1<<<nbScan, SCAN_B, 0, stream>>>(deg, offs, bsums);
  k_scan2<<<1, 128, 0, stream>>>(bsums, nbScan);
  k_scan3<<<nbScan, SCAN_B, 0, stream>>>(offs, bsums);
  k_bfill<<<NBUK, 256, 0, stream>>>(pr_pack, gcur, offs, dinv, wcsr);

  int nbG = (NN + 63) / 64;
  k_gemm128<<<nbG, 256, 0, stream>>>(x, WT1, t);
  k_agg128<<<NN / 4, 256, 0, stream>>>(t, offs, deg, wcsr, b1, h1);
  k_gemm64<<<nbG, 256, 0, stream>>>(h1, WT2, t);
  k_agg64<<<NN / 4, 256, 0, stream>>>(t, offs, deg, wcsr, b2, out);
}

// Round 9
// 222.850 us; speedup vs baseline: 1.2085x; 1.0446x over previous
//
#include <hip/hip_runtime.h>

#define NN 100000
#define NE 1600000
#define SCAN_B 1024

// bucketed counting sort params: 512 nodes per bucket
#define BSH 9
#define BSZ 512
#define NBUK 196          // ceil(NN / BSZ)
#define CAP 12288         // per-bucket pair capacity (mean 8163, huge margin)
#define CHUNK 4096        // edges per block in k_bucket

typedef _Float16 hs8 __attribute__((ext_vector_type(8)));
typedef float f32x4 __attribute__((ext_vector_type(4)));
typedef float f32x2 __attribute__((ext_vector_type(2)));
#define MFMA16H(a, b, c) __builtin_amdgcn_mfma_f32_16x16x32_f16(a, b, c, 0, 0, 0)

static inline size_t alignup(size_t x) { return (x + 255) & ~(size_t)255; }

union h8u { uint4 q; _Float16 h[8]; };

// ---------------- graph prep (bucketed counting sort) ----------------

// fused: gcur init + W1/W2 fp32->fp16 transposed converts
__global__ __launch_bounds__(256) void k_prep0(int* __restrict__ gcur,
                                               const float* __restrict__ W1, _Float16* __restrict__ WT1,
                                               const float* __restrict__ W2, _Float16* __restrict__ WT2) {
  int b = blockIdx.x, t = threadIdx.x;
  if (b < 64) {  // W1: [128,128] -> WT1[c][k]
    int i = b * 256 + t;
    int k = i >> 7, c = i & 127;
    WT1[c * 128 + k] = (_Float16)W1[i];
  } else if (b < 96) {  // W2: [128,64] -> WT2[c][k]
    int i = (b - 64) * 256 + t;
    int k = i >> 6, c = i & 63;
    WT2[c * 128 + k] = (_Float16)W2[i];
  } else {
    if (t < NBUK) gcur[t] = t * CAP;
  }
}

// bin edges into buckets; packed pair = (row<<9) | local_index
__global__ __launch_bounds__(256) void k_bucket(const int* __restrict__ row, const int* __restrict__ col,
                                                int* __restrict__ gcur, uint* __restrict__ pr_pack) {
  __shared__ int cnt[NBUK];
  int t = threadIdx.x;
  for (int i = t; i < NBUK; i += 256) cnt[i] = 0;
  __syncthreads();
  int e0 = blockIdx.x * CHUNK;
  int e1 = min(e0 + CHUNK, NE);
  for (int e = e0 + t; e < e1; e += 256) atomicAdd(&cnt[col[e] >> BSH], 1);
  __syncthreads();
  for (int i = t; i < NBUK; i += 256) {
    int c = cnt[i];
    cnt[i] = c ? atomicAdd(&gcur[i], c) : 0;
  }
  __syncthreads();
  for (int e = e0 + t; e < e1; e += 256) {
    int c = col[e];
    int p = atomicAdd(&cnt[c >> BSH], 1);
    pr_pack[p] = ((uint)row[e] << BSH) | (uint)(c & (BSZ - 1));
  }
}

// per-bucket degree count (+1 self loop) fused with dinv
__global__ __launch_bounds__(256) void k_bdeg(const uint* __restrict__ pr_pack, const int* __restrict__ gcur,
                                              int* __restrict__ deg, float* __restrict__ dinv) {
  __shared__ int dc[BSZ];
  int t = threadIdx.x, b = blockIdx.x;
  for (int i = t; i < BSZ; i += 256) dc[i] = 0;
  __syncthreads();
  int s = b * CAP;
  int n = min(gcur[b] - s, CAP);
  for (int i = t; i < n; i += 256) atomicAdd(&dc[pr_pack[s + i] & (BSZ - 1)], 1);
  __syncthreads();
  int nb0 = b << BSH;
  for (int i = t; i < BSZ; i += 256) {
    int node = nb0 + i;
    if (node < NN) {
      int d = dc[i] + 1;
      deg[node] = d;
      dinv[node] = rsqrtf((float)d);
    }
  }
}

// exclusive scan of deg (WITH self-loops) -> offs; CSR holds NE+NN entries
__global__ __launch_bounds__(SCAN_B) void k_scan1(const int* __restrict__ deg, int* __restrict__ offs,
                                                  int* __restrict__ bsums) {
  __shared__ int sm[SCAN_B];
  int i = blockIdx.x * SCAN_B + threadIdx.x;
  int v = (i < NN) ? deg[i] : 0;
  sm[threadIdx.x] = v;
  __syncthreads();
  for (int d = 1; d < SCAN_B; d <<= 1) {
    int t = (threadIdx.x >= d) ? sm[threadIdx.x - d] : 0;
    __syncthreads();
    sm[threadIdx.x] += t;
    __syncthreads();
  }
  if (i < NN) offs[i] = sm[threadIdx.x] - v;
  if (threadIdx.x == SCAN_B - 1) bsums[blockIdx.x] = sm[threadIdx.x];
}

__global__ __launch_bounds__(128) void k_scan2(int* __restrict__ bsums, int nb) {
  __shared__ int sm[128];
  int v = (threadIdx.x < nb) ? bsums[threadIdx.x] : 0;
  sm[threadIdx.x] = v;
  __syncthreads();
  for (int d = 1; d < 128; d <<= 1) {
    int t = (threadIdx.x >= d) ? sm[threadIdx.x - d] : 0;
    __syncthreads();
    sm[threadIdx.x] += t;
    __syncthreads();
  }
  if (threadIdx.x < nb) bsums[threadIdx.x] = sm[threadIdx.x] - v;
}

__global__ __launch_bounds__(SCAN_B) void k_scan3(int* __restrict__ offs, const int* __restrict__ bsums) {
  int i = blockIdx.x * SCAN_B + threadIdx.x;
  if (i < NN) offs[i] += bsums[blockIdx.x];
}

// weighted CSR incl. self-loops: entry = (src_row, fp32 weight)
__global__ __launch_bounds__(256) void k_bfill(const uint* __restrict__ pr_pack, const int* __restrict__ gcur,
                                               const int* __restrict__ offs, const float* __restrict__ dinv,
                                               uint2* __restrict__ wcsr) {
  __shared__ int loff[BSZ];
  __shared__ int cur[BSZ];
  __shared__ float dl[BSZ];
  int t = threadIdx.x, b = blockIdx.x;
  int nb0 = b << BSH;
  for (int i = t; i < BSZ; i += 256) {
    int node = nb0 + i;
    if (node < NN) {
      int o = offs[node];
      float d = dinv[node];
      loff[i] = o;
      dl[i] = d;
      cur[i] = 1;  // slot 0 = self loop
      wcsr[o] = make_uint2((uint)node, __float_as_uint(d * d));
    } else {
      loff[i] = 0; dl[i] = 0.f; cur[i] = 1;
    }
  }
  __syncthreads();
  int s = b * CAP;
  int n = min(gcur[b] - s, CAP);
  for (int i = t; i < n; i += 256) {
    uint prk = pr_pack[s + i];
    int li = (int)(prk & (BSZ - 1));
    uint r = prk >> BSH;
    int p = atomicAdd(&cur[li], 1);
    wcsr[loff[li] + p] = make_uint2(r, __float_as_uint(dinv[r] * dl[li]));
  }
}

// ---------------- dense transforms (fp16 MFMA) ----------------

// t8[N,128](fp8 e4m3) = x[N,128](f32) @ W1
__global__ __launch_bounds__(256) void k_gemm128(const float* __restrict__ x, const _Float16* __restrict__ WT,
                                                 unsigned char* __restrict__ t8) {
  int wave = threadIdx.x >> 6, lane = threadIdx.x & 63;
  int col0 = wave * 32;
  int lr = lane & 15;
  int lk = (lane >> 4) * 8;
  hs8 bfrag[2][4];
#pragma unroll
  for (int n = 0; n < 2; n++)
#pragma unroll
    for (int ks = 0; ks < 4; ks++)
      bfrag[n][ks] = *(const hs8*)&WT[(size_t)(col0 + n * 16 + lr) * 128 + ks * 32 + lk];
  int row0 = blockIdx.x * 64;
#pragma unroll 1
  for (int mt = 0; mt < 4; mt++) {
    int r0 = row0 + mt * 16;
    if (r0 >= NN) return;
    const float* xr = x + (size_t)(r0 + lr) * 128 + lk;
    f32x4 acc[2] = {{0.f, 0.f, 0.f, 0.f}, {0.f, 0.f, 0.f, 0.f}};
#pragma unroll
    for (int ks = 0; ks < 4; ks++) {
      float4 a0 = *(const float4*)&xr[ks * 32];
      float4 a1 = *(const float4*)&xr[ks * 32 + 4];
      hs8 af;
      af[0] = (_Float16)a0.x; af[1] = (_Float16)a0.y;
      af[2] = (_Float16)a0.z; af[3] = (_Float16)a0.w;
      af[4] = (_Float16)a1.x; af[5] = (_Float16)a1.y;
      af[6] = (_Float16)a1.z; af[7] = (_Float16)a1.w;
      acc[0] = MFMA16H(af, bfrag[0][ks], acc[0]);
      acc[1] = MFMA16H(af, bfrag[1][ks], acc[1]);
    }
    int rbase = r0 + (lane >> 4) * 4;
#pragma unroll
    for (int n = 0; n < 2; n++)
#pragma unroll
      for (int r = 0; r < 4; r++) {
        uint e = (uint)__builtin_amdgcn_cvt_pk_fp8_f32(acc[n][r], acc[n][r], 0, false);
        t8[(size_t)(rbase + r) * 128 + col0 + n * 16 + lr] = (unsigned char)(e & 0xffu);
      }
  }
}

// t2[N,64](fp16) = h[N,128](fp16) @ W2
__global__ __launch_bounds__(256) void k_gemm64(const _Float16* __restrict__ h, const _Float16* __restrict__ WT,
                                                _Float16* __restrict__ t2) {
  int wave = threadIdx.x >> 6, lane = threadIdx.x & 63;
  int col0 = wave * 16;
  int lr = lane & 15;
  int lk = (lane >> 4) * 8;
  hs8 bfrag[4];
#pragma unroll
  for (int ks = 0; ks < 4; ks++)
    bfrag[ks] = *(const hs8*)&WT[(size_t)(col0 + lr) * 128 + ks * 32 + lk];
  int row0 = blockIdx.x * 64;
#pragma unroll 1
  for (int mt = 0; mt < 4; mt++) {
    int r0 = row0 + mt * 16;
    if (r0 >= NN) return;
    const _Float16* hr = h + (size_t)(r0 + lr) * 128 + lk;
    f32x4 acc = {0.f, 0.f, 0.f, 0.f};
#pragma unroll
    for (int ks = 0; ks < 4; ks++) {
      hs8 af = *(const hs8*)&hr[ks * 32];
      acc = MFMA16H(af, bfrag[ks], acc);
    }
    int rbase = r0 + (lane >> 4) * 4;
#pragma unroll
    for (int r = 0; r < 4; r++)
      t2[(size_t)(rbase + r) * 64 + col0 + lr] = (_Float16)acc[r];
  }
}

// ---------------- aggregation (grouped-lane wide gathers, fp32 accum) ----------------

// layer 1: fp8 rows (128 B). 4 groups of 16 lanes; group g handles edge 4k+g;
// lane loads 8 B = 8 fp8 feats, decodes via cvt_pk_f32_fp8.
__global__ __launch_bounds__(256) void k_agg128(const unsigned char* __restrict__ t8, const int* __restrict__ offs,
                                                const int* __restrict__ deg, const uint2* __restrict__ wcsr,
                                                const float* __restrict__ bias, _Float16* __restrict__ out) {
  int wave = threadIdx.x >> 6, lane = threadIdx.x & 63;
  int node = blockIdx.x * 4 + wave;
  if (node >= NN) return;
  int g = lane >> 4, f = lane & 15;
  float acc[8] = {};
  int beg = offs[node];
  int cnt = deg[node];  // includes self-loop slot
  const char* tb = (const char*)t8;
  for (int base = 0; base < cnt; base += 64) {
    int m = min(64, cnt - base);
    uint2 pr = (lane < m) ? wcsr[beg + base + lane] : make_uint2(0u, 0u);
    int ridx = (int)pr.x;
    float wv = __uint_as_float(pr.y);
    int mm = (m + 3) >> 2;
    for (int k = 0; k < mm; k++) {
      int src = k * 4 + g;
      int r = __shfl(ridx, src);
      float s = __shfl(wv, src);  // 0 for padded slots
      uint2 u = *(const uint2*)(tb + (((size_t)(uint)r) << 7) + (f << 3));
      f32x2 p0 = __builtin_amdgcn_cvt_pk_f32_fp8(u.x, false);
      f32x2 p1 = __builtin_amdgcn_cvt_pk_f32_fp8(u.x, true);
      f32x2 p2 = __builtin_amdgcn_cvt_pk_f32_fp8(u.y, false);
      f32x2 p3 = __builtin_amdgcn_cvt_pk_f32_fp8(u.y, true);
      acc[0] = fmaf(p0[0], s, acc[0]);
      acc[1] = fmaf(p0[1], s, acc[1]);
      acc[2] = fmaf(p1[0], s, acc[2]);
      acc[3] = fmaf(p1[1], s, acc[3]);
      acc[4] = fmaf(p2[0], s, acc[4]);
      acc[5] = fmaf(p2[1], s, acc[5]);
      acc[6] = fmaf(p3[0], s, acc[6]);
      acc[7] = fmaf(p3[1], s, acc[7]);
    }
  }
#pragma unroll
  for (int j = 0; j < 8; j++) {
    acc[j] += __shfl_xor(acc[j], 16);
    acc[j] += __shfl_xor(acc[j], 32);
  }
  if (g == 0) {
    float4 b0 = *(const float4*)&bias[f * 8];
    float4 b1 = *(const float4*)&bias[f * 8 + 4];
    h8u st;
    st.h[0] = (_Float16)fmaxf(acc[0] + b0.x, 0.f);
    st.h[1] = (_Float16)fmaxf(acc[1] + b0.y, 0.f);
    st.h[2] = (_Float16)fmaxf(acc[2] + b0.z, 0.f);
    st.h[3] = (_Float16)fmaxf(acc[3] + b0.w, 0.f);
    st.h[4] = (_Float16)fmaxf(acc[4] + b1.x, 0.f);
    st.h[5] = (_Float16)fmaxf(acc[5] + b1.y, 0.f);
    st.h[6] = (_Float16)fmaxf(acc[6] + b1.z, 0.f);
    st.h[7] = (_Float16)fmaxf(acc[7] + b1.w, 0.f);
    *(uint4*)&out[(size_t)node * 128 + f * 8] = st.q;
  }
}

// layer 2: fp16 rows (128 B). 8 groups of 8 lanes; lane loads 16 B (8 fp16 feats)
__global__ __launch_bounds__(256) void k_agg64(const _Float16* __restrict__ t, const int* __restrict__ offs,
                                               const int* __restrict__ deg, const uint2* __restrict__ wcsr,
                                               const float* __restrict__ bias, float* __restrict__ out) {
  int wave = threadIdx.x >> 6, lane = threadIdx.x & 63;
  int node = blockIdx.x * 4 + wave;
  if (node >= NN) return;
  int g = lane >> 3, fl = lane & 7;
  float acc[8] = {};
  int beg = offs[node];
  int cnt = deg[node];
  const char* tb = (const char*)t;
  for (int base = 0; base < cnt; base += 64) {
    int m = min(64, cnt - base);
    uint2 pr = (lane < m) ? wcsr[beg + base + lane] : make_uint2(0u, 0u);
    int ridx = (int)pr.x;
    float wv = __uint_as_float(pr.y);
    int mm = (m + 7) >> 3;
    for (int k = 0; k < mm; k++) {
      int src = k * 8 + g;
      int r = __shfl(ridx, src);
      float s = __shfl(wv, src);
      h8u u;
      u.q = *(const uint4*)(tb + (((size_t)(uint)r) << 7) + (fl << 4));
      acc[0] = fmaf((float)u.h[0], s, acc[0]);
      acc[1] = fmaf((float)u.h[1], s, acc[1]);
      acc[2] = fmaf((float)u.h[2], s, acc[2]);
      acc[3] = fmaf((float)u.h[3], s, acc[3]);
      acc[4] = fmaf((float)u.h[4], s, acc[4]);
      acc[5] = fmaf((float)u.h[5], s, acc[5]);
      acc[6] = fmaf((float)u.h[6], s, acc[6]);
      acc[7] = fmaf((float)u.h[7], s, acc[7]);
    }
  }
#pragma unroll
  for (int j = 0; j < 8; j++) {
    acc[j] += __shfl_xor(acc[j], 8);
    acc[j] += __shfl_xor(acc[j], 16);
    acc[j] += __shfl_xor(acc[j], 32);
  }
  if (g == 0) {
    float4 b0 = *(const float4*)&bias[fl * 8];
    float4 b1 = *(const float4*)&bias[fl * 8 + 4];
    float4 o0 = make_float4(acc[0] + b0.x, acc[1] + b0.y, acc[2] + b0.z, acc[3] + b0.w);
    float4 o1 = make_float4(acc[4] + b1.x, acc[5] + b1.y, acc[6] + b1.z, acc[7] + b1.w);
    *(float4*)&out[(size_t)node * 64 + fl * 8] = o0;
    *(float4*)&out[(size_t)node * 64 + fl * 8 + 4] = o1;
  }
}

// ---------------- host ----------------

extern "C" void kernel_launch(void* const* d_in, const int* in_sizes, int n_in,
                              void* d_out, int out_size, void* d_ws, size_t ws_size,
                              hipStream_t stream) {
  const float* x  = (const float*)d_in[0];
  const int*   ei = (const int*)d_in[1];
  const float* W1 = (const float*)d_in[2];
  const float* b1 = (const float*)d_in[3];
  const float* W2 = (const float*)d_in[4];
  const float* b2 = (const float*)d_in[5];
  float* out = (float*)d_out;

  char* p = (char*)d_ws;
  int* deg       = (int*)p;      p += alignup((size_t)NN * 4);
  int* gcur      = (int*)p;      p += alignup((size_t)NBUK * 4);
  int* offs      = (int*)p;      p += alignup((size_t)NN * 4);
  int* bsums     = (int*)p;      p += alignup(128 * 4);
  float* dinv    = (float*)p;    p += alignup((size_t)NN * 4);
  uint2* wcsr    = (uint2*)p;    p += alignup((size_t)(NE + NN + 64) * 8);
  _Float16* WT1  = (_Float16*)p; p += alignup(128 * 128 * 2);
  _Float16* WT2  = (_Float16*)p; p += alignup(64 * 128 * 2);
  unsigned char* t8 = (unsigned char*)p; p += alignup((size_t)NN * 128);
  _Float16* t2   = (_Float16*)p; p += alignup((size_t)NN * 64 * 2);
  _Float16* h1   = (_Float16*)p; p += alignup((size_t)NN * 128 * 2);
  // packed pair buffer aliases t2 (dead until k_gemm64 writes it); 9.6 MB <= 12.8 MB
  uint* pr_pack  = (uint*)t2;
  (void)ws_size; (void)in_sizes; (void)n_in; (void)out_size;

  const int* row = ei;
  const int* col = ei + NE;

  int nbScan = (NN + SCAN_B - 1) / SCAN_B;
  int nbB = (NE + CHUNK - 1) / CHUNK;

  k_prep0<<<97, 256, 0, stream>>>(gcur, W1, WT1, W2, WT2);
  k_bucket<<<nbB, 256, 0, stream>>>(row, col, gcur, pr_pack);
  k_bdeg<<<NBUK, 256, 0, stream>>>(pr_pack, gcur, deg, dinv);
  k_scan1<<<nbScan, SCAN_B, 0, stream>>>(deg, offs, bsums);
  k_scan2<<<1, 128, 0, stream>>>(bsums, nbScan);
  k_scan3<<<nbScan, SCAN_B, 0, stream>>>(offs, bsums);
  k_bfill<<<NBUK, 256, 0, stream>>>(pr_pack, gcur, offs, dinv, wcsr);

  int nbG = (NN + 63) / 64;
  k_gemm128<<<nbG, 256, 0, stream>>>(x, WT1, t8);
  k_agg128<<<NN / 4, 256, 0, stream>>>(t8, offs, deg, wcsr, b1, h1);
  k_gemm64<<<nbG, 256, 0, stream>>>(h1, WT2, t2);
  k_agg64<<<NN / 4, 256, 0, stream>>>(t2, offs, deg, wcsr, b2, out);
}

// Round 10
// 195.455 us; speedup vs baseline: 1.3779x; 1.1402x over previous
//
#include <hip/hip_runtime.h>

#define NN 100000
#define NE 1600000

// bucketed counting sort params: 512 nodes per bucket
#define BSH 9
#define BSZ 512
#define NBUK 196          // ceil(NN / BSZ)
#define CAP 12288         // per-bucket pair capacity (mean 8163, huge margin)
#define CHUNK 4096        // edges per block in k_bucket
#define EPT 16            // edges per thread in k_bucket (CHUNK/256)

typedef _Float16 hs8 __attribute__((ext_vector_type(8)));
typedef float f32x4 __attribute__((ext_vector_type(4)));
typedef float f32x2 __attribute__((ext_vector_type(2)));
#define MFMA16H(a, b, c) __builtin_amdgcn_mfma_f32_16x16x32_f16(a, b, c, 0, 0, 0)

static inline size_t alignup(size_t x) { return (x + 255) & ~(size_t)255; }

union h8u { uint4 q; _Float16 h[8]; };

// ---------------- graph prep (bucketed counting sort) ----------------

// fused: gcur init + W1/W2 fp32->fp16 transposed converts
__global__ __launch_bounds__(256) void k_prep0(int* __restrict__ gcur,
                                               const float* __restrict__ W1, _Float16* __restrict__ WT1,
                                               const float* __restrict__ W2, _Float16* __restrict__ WT2) {
  int b = blockIdx.x, t = threadIdx.x;
  if (b < 64) {  // W1: [128,128] -> WT1[c][k]
    int i = b * 256 + t;
    int k = i >> 7, c = i & 127;
    WT1[c * 128 + k] = (_Float16)W1[i];
  } else if (b < 96) {  // W2: [128,64] -> WT2[c][k]
    int i = (b - 64) * 256 + t;
    int k = i >> 6, c = i & 63;
    WT2[c * 128 + k] = (_Float16)W2[i];
  } else {
    if (t < NBUK) gcur[t] = t * CAP;
  }
}

// bin edges into buckets; edge chunk register-cached (col read once)
__global__ __launch_bounds__(256) void k_bucket(const int* __restrict__ row, const int* __restrict__ col,
                                                int* __restrict__ gcur, uint* __restrict__ pr_pack) {
  __shared__ int cnt[NBUK];
  int t = threadIdx.x;
  for (int i = t; i < NBUK; i += 256) cnt[i] = 0;
  __syncthreads();
  int e0 = blockIdx.x * CHUNK;
  int rr[EPT], cc[EPT];
#pragma unroll
  for (int i = 0; i < EPT; i++) {
    int e = e0 + t + i * 256;
    bool ok = e < NE;
    cc[i] = ok ? col[e] : -1;
    rr[i] = ok ? row[e] : 0;
  }
#pragma unroll
  for (int i = 0; i < EPT; i++)
    if (cc[i] >= 0) atomicAdd(&cnt[cc[i] >> BSH], 1);
  __syncthreads();
  for (int i = t; i < NBUK; i += 256) {
    int c = cnt[i];
    cnt[i] = c ? atomicAdd(&gcur[i], c) : 0;  // cnt becomes running global cursor
  }
  __syncthreads();
#pragma unroll
  for (int i = 0; i < EPT; i++)
    if (cc[i] >= 0) {
      int p = atomicAdd(&cnt[cc[i] >> BSH], 1);
      pr_pack[p] = ((uint)rr[i] << BSH) | (uint)(cc[i] & (BSZ - 1));
    }
}

// per-bucket degree count (+1 self loop), dinv, and bucket degree total
__global__ __launch_bounds__(256) void k_bdeg(const uint* __restrict__ pr_pack, const int* __restrict__ gcur,
                                              int* __restrict__ deg, float* __restrict__ dinv,
                                              int* __restrict__ bsums) {
  __shared__ int dc[BSZ];
  int t = threadIdx.x, b = blockIdx.x;
  for (int i = t; i < BSZ; i += 256) dc[i] = 0;
  __syncthreads();
  int s = b * CAP;
  int n = min(gcur[b] - s, CAP);
  for (int i = t; i < n; i += 256) atomicAdd(&dc[pr_pack[s + i] & (BSZ - 1)], 1);
  __syncthreads();
  int nb0 = b << BSH;
  for (int i = t; i < BSZ; i += 256) {
    int node = nb0 + i;
    if (node < NN) {
      int d = dc[i] + 1;
      deg[node] = d;
      dinv[node] = rsqrtf((float)d);
    }
  }
  if (t == 0) bsums[b] = n + min(BSZ, NN - nb0);  // sum of deg over valid nodes
}

// single-block exclusive scan of 196 bucket totals
__global__ __launch_bounds__(256) void k_scanB(int* __restrict__ bsums) {
  __shared__ int sm[256];
  int t = threadIdx.x;
  int v = (t < NBUK) ? bsums[t] : 0;
  sm[t] = v;
  __syncthreads();
  for (int d = 1; d < 256; d <<= 1) {
    int tmp = (t >= d) ? sm[t - d] : 0;
    __syncthreads();
    sm[t] += tmp;
    __syncthreads();
  }
  if (t < NBUK) bsums[t] = sm[t] - v;
}

// per-bucket: local 512-entry exclusive scan of deg -> offs, then weighted-CSR fill
// wcsr entry = (src_row, fp32 weight); slot 0 of each node = self loop
__global__ __launch_bounds__(256) void k_bfill(const uint* __restrict__ pr_pack, const int* __restrict__ gcur,
                                               const int* __restrict__ deg, const float* __restrict__ dinv,
                                               const int* __restrict__ bsums, int* __restrict__ offs,
                                               uint2* __restrict__ wcsr) {
  __shared__ int loff[BSZ];
  __shared__ int cur[BSZ];
  __shared__ float dl[BSZ];
  __shared__ int tsum[256];
  int t = threadIdx.x, b = blockIdx.x;
  int nb0 = b << BSH;
  int i0 = 2 * t, i1 = i0 + 1;
  int n0 = nb0 + i0, n1 = nb0 + i1;
  int d0 = (n0 < NN) ? deg[n0] : 0;
  int d1 = (n1 < NN) ? deg[n1] : 0;
  int v = d0 + d1;
  tsum[t] = v;
  __syncthreads();
  for (int d = 1; d < 256; d <<= 1) {
    int tmp = (t >= d) ? tsum[t - d] : 0;
    __syncthreads();
    tsum[t] += tmp;
    __syncthreads();
  }
  int base = bsums[b] + tsum[t] - v;  // exclusive local offset + bucket base
  float dv0 = (n0 < NN) ? dinv[n0] : 0.f;
  float dv1 = (n1 < NN) ? dinv[n1] : 0.f;
  loff[i0] = base;
  loff[i1] = base + d0;
  dl[i0] = dv0;
  dl[i1] = dv1;
  cur[i0] = 1;  // slot 0 = self loop
  cur[i1] = 1;
  if (n0 < NN) {
    offs[n0] = base;
    wcsr[base] = make_uint2((uint)n0, __float_as_uint(dv0 * dv0));
  }
  if (n1 < NN) {
    offs[n1] = base + d0;
    wcsr[base + d0] = make_uint2((uint)n1, __float_as_uint(dv1 * dv1));
  }
  __syncthreads();
  int s = b * CAP;
  int n = min(gcur[b] - s, CAP);
  for (int i = t; i < n; i += 256) {
    uint prk = pr_pack[s + i];
    int li = (int)(prk & (BSZ - 1));
    uint r = prk >> BSH;
    int p = atomicAdd(&cur[li], 1);
    wcsr[loff[li] + p] = make_uint2(r, __float_as_uint(dinv[r] * dl[li]));
  }
}

// ---------------- dense transforms (fp16 MFMA) ----------------

// t8[N,128](fp8 e4m3) = x[N,128](f32) @ W1
__global__ __launch_bounds__(256) void k_gemm128(const float* __restrict__ x, const _Float16* __restrict__ WT,
                                                 unsigned char* __restrict__ t8) {
  int wave = threadIdx.x >> 6, lane = threadIdx.x & 63;
  int col0 = wave * 32;
  int lr = lane & 15;
  int lk = (lane >> 4) * 8;
  hs8 bfrag[2][4];
#pragma unroll
  for (int n = 0; n < 2; n++)
#pragma unroll
    for (int ks = 0; ks < 4; ks++)
      bfrag[n][ks] = *(const hs8*)&WT[(size_t)(col0 + n * 16 + lr) * 128 + ks * 32 + lk];
  int row0 = blockIdx.x * 64;
#pragma unroll 1
  for (int mt = 0; mt < 4; mt++) {
    int r0 = row0 + mt * 16;
    if (r0 >= NN) return;
    const float* xr = x + (size_t)(r0 + lr) * 128 + lk;
    f32x4 acc[2] = {{0.f, 0.f, 0.f, 0.f}, {0.f, 0.f, 0.f, 0.f}};
#pragma unroll
    for (int ks = 0; ks < 4; ks++) {
      float4 a0 = *(const float4*)&xr[ks * 32];
      float4 a1 = *(const float4*)&xr[ks * 32 + 4];
      hs8 af;
      af[0] = (_Float16)a0.x; af[1] = (_Float16)a0.y;
      af[2] = (_Float16)a0.z; af[3] = (_Float16)a0.w;
      af[4] = (_Float16)a1.x; af[5] = (_Float16)a1.y;
      af[6] = (_Float16)a1.z; af[7] = (_Float16)a1.w;
      acc[0] = MFMA16H(af, bfrag[0][ks], acc[0]);
      acc[1] = MFMA16H(af, bfrag[1][ks], acc[1]);
    }
    int rbase = r0 + (lane >> 4) * 4;
#pragma unroll
    for (int n = 0; n < 2; n++)
#pragma unroll
      for (int r = 0; r < 4; r++) {
        uint e = (uint)__builtin_amdgcn_cvt_pk_fp8_f32(acc[n][r], acc[n][r], 0, false);
        t8[(size_t)(rbase + r) * 128 + col0 + n * 16 + lr] = (unsigned char)(e & 0xffu);
      }
  }
}

// t2[N,64](fp16) = h[N,128](fp16) @ W2
__global__ __launch_bounds__(256) void k_gemm64(const _Float16* __restrict__ h, const _Float16* __restrict__ WT,
                                                _Float16* __restrict__ t2) {
  int wave = threadIdx.x >> 6, lane = threadIdx.x & 63;
  int col0 = wave * 16;
  int lr = lane & 15;
  int lk = (lane >> 4) * 8;
  hs8 bfrag[4];
#pragma unroll
  for (int ks = 0; ks < 4; ks++)
    bfrag[ks] = *(const hs8*)&WT[(size_t)(col0 + lr) * 128 + ks * 32 + lk];
  int row0 = blockIdx.x * 64;
#pragma unroll 1
  for (int mt = 0; mt < 4; mt++) {
    int r0 = row0 + mt * 16;
    if (r0 >= NN) return;
    const _Float16* hr = h + (size_t)(r0 + lr) * 128 + lk;
    f32x4 acc = {0.f, 0.f, 0.f, 0.f};
#pragma unroll
    for (int ks = 0; ks < 4; ks++) {
      hs8 af = *(const hs8*)&hr[ks * 32];
      acc = MFMA16H(af, bfrag[ks], acc);
    }
    int rbase = r0 + (lane >> 4) * 4;
#pragma unroll
    for (int r = 0; r < 4; r++)
      t2[(size_t)(rbase + r) * 64 + col0 + lr] = (_Float16)acc[r];
  }
}

// ---------------- aggregation (2 nodes/wave, direct bcast wcsr loads, pipelined) ----------------

// layer 1: fp8 rows (128 B). half (32 lanes) per node; 2 subgroups of 16 per half.
__global__ __launch_bounds__(256) void k_agg128(const unsigned char* __restrict__ t8, const int* __restrict__ offs,
                                                const int* __restrict__ deg, const uint2* __restrict__ wcsr,
                                                const float* __restrict__ bias, _Float16* __restrict__ out) {
  int wave = threadIdx.x >> 6, lane = threadIdx.x & 63;
  int half = lane >> 5;          // 0: node A, 1: node B
  int sub = (lane >> 4) & 1;     // edge parity within half
  int f = lane & 15;             // feature lane (8 fp8 feats)
  int node = blockIdx.x * 8 + wave * 2 + half;
  int beg = offs[node];
  int d = deg[node];             // includes self-loop
  const char* tb = (const char*)t8;
  float acc[8] = {};
  int trips = (d + 1) >> 1;
  uint2 e = (sub < d) ? wcsr[beg + sub] : make_uint2(0u, 0u);
#pragma unroll 1
  for (int k = 0; k < trips; k++) {
    int ns = (k + 1) * 2 + sub;
    uint2 en = (ns < d) ? wcsr[beg + ns] : make_uint2(0u, 0u);
    float s = __uint_as_float(e.y);  // 0 for padded slots
    uint2 u = *(const uint2*)(tb + (((size_t)e.x) << 7) + (f << 3));
    f32x2 p0 = __builtin_amdgcn_cvt_pk_f32_fp8(u.x, false);
    f32x2 p1 = __builtin_amdgcn_cvt_pk_f32_fp8(u.x, true);
    f32x2 p2 = __builtin_amdgcn_cvt_pk_f32_fp8(u.y, false);
    f32x2 p3 = __builtin_amdgcn_cvt_pk_f32_fp8(u.y, true);
    acc[0] = fmaf(p0[0], s, acc[0]);
    acc[1] = fmaf(p0[1], s, acc[1]);
    acc[2] = fmaf(p1[0], s, acc[2]);
    acc[3] = fmaf(p1[1], s, acc[3]);
    acc[4] = fmaf(p2[0], s, acc[4]);
    acc[5] = fmaf(p2[1], s, acc[5]);
    acc[6] = fmaf(p3[0], s, acc[6]);
    acc[7] = fmaf(p3[1], s, acc[7]);
    e = en;
  }
#pragma unroll
  for (int j = 0; j < 8; j++) acc[j] += __shfl_xor(acc[j], 16);
  if (sub == 0) {
    float4 b0 = *(const float4*)&bias[f * 8];
    float4 b1 = *(const float4*)&bias[f * 8 + 4];
    h8u st;
    st.h[0] = (_Float16)fmaxf(acc[0] + b0.x, 0.f);
    st.h[1] = (_Float16)fmaxf(acc[1] + b0.y, 0.f);
    st.h[2] = (_Float16)fmaxf(acc[2] + b0.z, 0.f);
    st.h[3] = (_Float16)fmaxf(acc[3] + b0.w, 0.f);
    st.h[4] = (_Float16)fmaxf(acc[4] + b1.x, 0.f);
    st.h[5] = (_Float16)fmaxf(acc[5] + b1.y, 0.f);
    st.h[6] = (_Float16)fmaxf(acc[6] + b1.z, 0.f);
    st.h[7] = (_Float16)fmaxf(acc[7] + b1.w, 0.f);
    *(uint4*)&out[(size_t)node * 128 + f * 8] = st.q;
  }
}

// layer 2: fp16 rows (128 B). half (32 lanes) per node; 4 subgroups of 8 per half.
__global__ __launch_bounds__(256) void k_agg64(const _Float16* __restrict__ t, const int* __restrict__ offs,
                                               const int* __restrict__ deg, const uint2* __restrict__ wcsr,
                                               const float* __restrict__ bias, float* __restrict__ out) {
  int wave = threadIdx.x >> 6, lane = threadIdx.x & 63;
  int half = lane >> 5;
  int sub = (lane >> 3) & 3;     // edge slot within half
  int f8 = lane & 7;             // feature lane (8 fp16 feats)
  int node = blockIdx.x * 8 + wave * 2 + half;
  int beg = offs[node];
  int d = deg[node];
  const char* tb = (const char*)t;
  float acc[8] = {};
  int trips = (d + 3) >> 2;
  uint2 e = (sub < d) ? wcsr[beg + sub] : make_uint2(0u, 0u);
#pragma unroll 1
  for (int k = 0; k < trips; k++) {
    int ns = (k + 1) * 4 + sub;
    uint2 en = (ns < d) ? wcsr[beg + ns] : make_uint2(0u, 0u);
    float s = __uint_as_float(e.y);
    h8u u;
    u.q = *(const uint4*)(tb + (((size_t)e.x) << 7) + (f8 << 4));
    acc[0] = fmaf((float)u.h[0], s, acc[0]);
    acc[1] = fmaf((float)u.h[1], s, acc[1]);
    acc[2] = fmaf((float)u.h[2], s, acc[2]);
    acc[3] = fmaf((float)u.h[3], s, acc[3]);
    acc[4] = fmaf((float)u.h[4], s, acc[4]);
    acc[5] = fmaf((float)u.h[5], s, acc[5]);
    acc[6] = fmaf((float)u.h[6], s, acc[6]);
    acc[7] = fmaf((float)u.h[7], s, acc[7]);
    e = en;
  }
#pragma unroll
  for (int j = 0; j < 8; j++) {
    acc[j] += __shfl_xor(acc[j], 8);
    acc[j] += __shfl_xor(acc[j], 16);
  }
  if (sub == 0) {
    float4 b0 = *(const float4*)&bias[f8 * 8];
    float4 b1 = *(const float4*)&bias[f8 * 8 + 4];
    float4 o0 = make_float4(acc[0] + b0.x, acc[1] + b0.y, acc[2] + b0.z, acc[3] + b0.w);
    float4 o1 = make_float4(acc[4] + b1.x, acc[5] + b1.y, acc[6] + b1.z, acc[7] + b1.w);
    *(float4*)&out[(size_t)node * 64 + f8 * 8] = o0;
    *(float4*)&out[(size_t)node * 64 + f8 * 8 + 4] = o1;
  }
}

// ---------------- host ----------------

extern "C" void kernel_launch(void* const* d_in, const int* in_sizes, int n_in,
                              void* d_out, int out_size, void* d_ws, size_t ws_size,
                              hipStream_t stream) {
  const float* x  = (const float*)d_in[0];
  const int*   ei = (const int*)d_in[1];
  const float* W1 = (const float*)d_in[2];
  const float* b1 = (const float*)d_in[3];
  const float* W2 = (const float*)d_in[4];
  const float* b2 = (const float*)d_in[5];
  float* out = (float*)d_out;

  char* p = (char*)d_ws;
  int* deg       = (int*)p;      p += alignup((size_t)NN * 4);
  int* gcur      = (int*)p;      p += alignup((size_t)NBUK * 4);
  int* offs      = (int*)p;      p += alignup((size_t)NN * 4);
  int* bsums     = (int*)p;      p += alignup(256 * 4);
  float* dinv    = (float*)p;    p += alignup((size_t)NN * 4);
  uint2* wcsr    = (uint2*)p;    p += alignup((size_t)(NE + NN + 64) * 8);
  _Float16* WT1  = (_Float16*)p; p += alignup(128 * 128 * 2);
  _Float16* WT2  = (_Float16*)p; p += alignup(64 * 128 * 2);
  unsigned char* t8 = (unsigned char*)p; p += alignup((size_t)NN * 128);
  _Float16* t2   = (_Float16*)p; p += alignup((size_t)NN * 64 * 2);
  _Float16* h1   = (_Float16*)p; p += alignup((size_t)NN * 128 * 2);
  // packed pair buffer aliases t2 (dead until k_gemm64 writes it); 6.4 MB <= 12.8 MB
  uint* pr_pack  = (uint*)t2;
  (void)ws_size; (void)in_sizes; (void)n_in; (void)out_size;

  const int* row = ei;
  const int* col = ei + NE;

  int nbB = (NE + CHUNK - 1) / CHUNK;

  k_prep0<<<97, 256, 0, stream>>>(gcur, W1, WT1, W2, WT2);
  k_bucket<<<nbB, 256, 0, stream>>>(row, col, gcur, pr_pack);
  k_bdeg<<<NBUK, 256, 0, stream>>>(pr_pack, gcur, deg, dinv, bsums);
  k_scanB<<<1, 256, 0, stream>>>(bsums);
  k_bfill<<<NBUK, 256, 0, stream>>>(pr_pack, gcur, deg, dinv, bsums, offs, wcsr);

  int nbG = (NN + 63) / 64;
  int nbA = NN / 8;
  k_gemm128<<<nbG, 256, 0, stream>>>(x, WT1, t8);
  k_agg128<<<nbA, 256, 0, stream>>>(t8, offs, deg, wcsr, b1, h1);
  k_gemm64<<<nbG, 256, 0, stream>>>(h1, WT2, t2);
  k_agg64<<<nbA, 256, 0, stream>>>(t2, offs, deg, wcsr, b2, out);
}

// Round 11
// 183.455 us; speedup vs baseline: 1.4680x; 1.0654x over previous
//
#include <hip/hip_runtime.h>

#define NN 100000
#define NE 1600000

// bucketed counting sort params: 512 nodes per bucket
#define BSH 9
#define BSZ 512
#define NBUK 196          // ceil(NN / BSZ)
#define CAP 12288         // per-bucket pair capacity (mean 8163, huge margin)
#define CHUNK 4096        // edges per block in bucket phase
#define EPT 16            // edges per thread (CHUNK/256)

typedef _Float16 hs8 __attribute__((ext_vector_type(8)));
typedef float f32x4 __attribute__((ext_vector_type(4)));
typedef float f32x2 __attribute__((ext_vector_type(2)));
#define MFMA16H(a, b, c) __builtin_amdgcn_mfma_f32_16x16x32_f16(a, b, c, 0, 0, 0)

static inline size_t alignup(size_t x) { return (x + 255) & ~(size_t)255; }

union h8u { uint4 q; _Float16 h[8]; };

// ---------------- prep0: gcur/gtotal init + W converts ----------------

__global__ __launch_bounds__(256) void k_prep0(int* __restrict__ gcur, int* __restrict__ gtotal,
                                               const float* __restrict__ W1, _Float16* __restrict__ WT1,
                                               const float* __restrict__ W2, _Float16* __restrict__ WT2) {
  int b = blockIdx.x, t = threadIdx.x;
  if (b < 64) {  // W1: [128,128] -> WT1[c][k]
    int i = b * 256 + t;
    int k = i >> 7, c = i & 127;
    WT1[c * 128 + k] = (_Float16)W1[i];
  } else if (b < 96) {  // W2: [128,64] -> WT2[c][k]
    int i = (b - 64) * 256 + t;
    int k = i >> 6, c = i & 63;
    WT2[c * 128 + k] = (_Float16)W2[i];
  } else {
    if (t < NBUK) gcur[t] = t * CAP;
    if (t == 0) *gtotal = 0;
  }
}

// ---------------- gemm128 body (device fn, used by fused kernel) ----------------

__device__ __forceinline__ void gemm128_body(const float* __restrict__ x, const _Float16* __restrict__ WT,
                                             unsigned char* __restrict__ t8, int bid) {
  int wave = threadIdx.x >> 6, lane = threadIdx.x & 63;
  int col0 = wave * 32;
  int lr = lane & 15;
  int lk = (lane >> 4) * 8;
  hs8 bfrag[2][4];
#pragma unroll
  for (int n = 0; n < 2; n++)
#pragma unroll
    for (int ks = 0; ks < 4; ks++)
      bfrag[n][ks] = *(const hs8*)&WT[(size_t)(col0 + n * 16 + lr) * 128 + ks * 32 + lk];
  int row0 = bid * 64;
#pragma unroll 1
  for (int mt = 0; mt < 4; mt++) {
    int r0 = row0 + mt * 16;
    if (r0 >= NN) return;
    const float* xr = x + (size_t)(r0 + lr) * 128 + lk;
    f32x4 acc[2] = {{0.f, 0.f, 0.f, 0.f}, {0.f, 0.f, 0.f, 0.f}};
#pragma unroll
    for (int ks = 0; ks < 4; ks++) {
      float4 a0 = *(const float4*)&xr[ks * 32];
      float4 a1 = *(const float4*)&xr[ks * 32 + 4];
      hs8 af;
      af[0] = (_Float16)a0.x; af[1] = (_Float16)a0.y;
      af[2] = (_Float16)a0.z; af[3] = (_Float16)a0.w;
      af[4] = (_Float16)a1.x; af[5] = (_Float16)a1.y;
      af[6] = (_Float16)a1.z; af[7] = (_Float16)a1.w;
      acc[0] = MFMA16H(af, bfrag[0][ks], acc[0]);
      acc[1] = MFMA16H(af, bfrag[1][ks], acc[1]);
    }
    int rbase = r0 + (lane >> 4) * 4;
#pragma unroll
    for (int n = 0; n < 2; n++)
#pragma unroll
      for (int r = 0; r < 4; r++) {
        uint e = (uint)__builtin_amdgcn_cvt_pk_fp8_f32(acc[n][r], acc[n][r], 0, false);
        t8[(size_t)(rbase + r) * 128 + col0 + n * 16 + lr] = (unsigned char)(e & 0xffu);
      }
  }
}

// ---------------- fused: edge bucketing (blocks < nbB) + gemm128 (rest) ----------------

__global__ __launch_bounds__(256) void k_fused1(const int* __restrict__ row, const int* __restrict__ col,
                                                int* __restrict__ gcur, uint* __restrict__ pr_pack,
                                                const float* __restrict__ x, const _Float16* __restrict__ WT,
                                                unsigned char* __restrict__ t8, int nbB) {
  if ((int)blockIdx.x >= nbB) {
    gemm128_body(x, WT, t8, (int)blockIdx.x - nbB);
    return;
  }
  __shared__ int cnt[NBUK];
  int t = threadIdx.x;
  for (int i = t; i < NBUK; i += 256) cnt[i] = 0;
  __syncthreads();
  int e0 = blockIdx.x * CHUNK;
  int rr[EPT], cc[EPT];
#pragma unroll
  for (int i = 0; i < EPT; i++) {
    int e = e0 + t + i * 256;
    bool ok = e < NE;
    cc[i] = ok ? col[e] : -1;
    rr[i] = ok ? row[e] : 0;
  }
#pragma unroll
  for (int i = 0; i < EPT; i++)
    if (cc[i] >= 0) atomicAdd(&cnt[cc[i] >> BSH], 1);
  __syncthreads();
  for (int i = t; i < NBUK; i += 256) {
    int c = cnt[i];
    cnt[i] = c ? atomicAdd(&gcur[i], c) : 0;  // cnt becomes running global cursor
  }
  __syncthreads();
#pragma unroll
  for (int i = 0; i < EPT; i++)
    if (cc[i] >= 0) {
      int p = atomicAdd(&cnt[cc[i] >> BSH], 1);
      pr_pack[p] = ((uint)rr[i] << BSH) | (uint)(cc[i] & (BSZ - 1));
    }
}

// ---------------- per-bucket degree count (+1 self loop) + dinv ----------------

__global__ __launch_bounds__(256) void k_bdeg(const uint* __restrict__ pr_pack, const int* __restrict__ gcur,
                                              int* __restrict__ deg, float* __restrict__ dinv) {
  __shared__ int dc[BSZ];
  int t = threadIdx.x, b = blockIdx.x;
  for (int i = t; i < BSZ; i += 256) dc[i] = 0;
  __syncthreads();
  int s = b * CAP;
  int n = min(gcur[b] - s, CAP);
  for (int i = t; i < n; i += 256) atomicAdd(&dc[pr_pack[s + i] & (BSZ - 1)], 1);
  __syncthreads();
  int nb0 = b << BSH;
  for (int i = t; i < BSZ; i += 256) {
    int node = nb0 + i;
    if (node < NN) {
      int d = dc[i] + 1;
      deg[node] = d;
      dinv[node] = rsqrtf((float)d);
    }
  }
}

// ---------------- per-bucket: atomic CSR base alloc + local scan + weighted fill ----------------
// wcsr entry = (src_row, fp32 weight); slot 0 of each node = self loop

__global__ __launch_bounds__(256) void k_bfill(const uint* __restrict__ pr_pack, const int* __restrict__ gcur,
                                               const int* __restrict__ deg, const float* __restrict__ dinv,
                                               int* __restrict__ gtotal, int* __restrict__ offs,
                                               uint2* __restrict__ wcsr) {
  __shared__ int loff[BSZ];
  __shared__ int cur[BSZ];
  __shared__ float dl[BSZ];
  __shared__ int tsum[256];
  __shared__ int sbase;
  int t = threadIdx.x, b = blockIdx.x;
  int nb0 = b << BSH;
  int i0 = 2 * t, i1 = i0 + 1;
  int n0 = nb0 + i0, n1 = nb0 + i1;
  int d0 = (n0 < NN) ? deg[n0] : 0;
  int d1 = (n1 < NN) ? deg[n1] : 0;
  int v = d0 + d1;
  tsum[t] = v;
  __syncthreads();
  for (int d = 1; d < 256; d <<= 1) {
    int tmp = (t >= d) ? tsum[t - d] : 0;
    __syncthreads();
    tsum[t] += tmp;
    __syncthreads();
  }
  if (t == 255) sbase = atomicAdd(gtotal, tsum[255]);
  __syncthreads();
  int base = sbase + tsum[t] - v;  // exclusive local offset + bucket base
  float dv0 = (n0 < NN) ? dinv[n0] : 0.f;
  float dv1 = (n1 < NN) ? dinv[n1] : 0.f;
  loff[i0] = base;
  loff[i1] = base + d0;
  dl[i0] = dv0;
  dl[i1] = dv1;
  cur[i0] = 1;  // slot 0 = self loop
  cur[i1] = 1;
  if (n0 < NN) {
    offs[n0] = base;
    wcsr[base] = make_uint2((uint)n0, __float_as_uint(dv0 * dv0));
  }
  if (n1 < NN) {
    offs[n1] = base + d0;
    wcsr[base + d0] = make_uint2((uint)n1, __float_as_uint(dv1 * dv1));
  }
  __syncthreads();
  int s = b * CAP;
  int n = min(gcur[b] - s, CAP);
  for (int i = t; i < n; i += 256) {
    uint prk = pr_pack[s + i];
    int li = (int)(prk & (BSZ - 1));
    uint r = prk >> BSH;
    int p = atomicAdd(&cur[li], 1);
    wcsr[loff[li] + p] = make_uint2(r, __float_as_uint(dinv[r] * dl[li]));
  }
}

// ---------------- gemm64: t2[N,64](fp16) = h[N,128](fp16) @ W2 ----------------

__global__ __launch_bounds__(256) void k_gemm64(const _Float16* __restrict__ h, const _Float16* __restrict__ WT,
                                                _Float16* __restrict__ t2) {
  int wave = threadIdx.x >> 6, lane = threadIdx.x & 63;
  int col0 = wave * 16;
  int lr = lane & 15;
  int lk = (lane >> 4) * 8;
  hs8 bfrag[4];
#pragma unroll
  for (int ks = 0; ks < 4; ks++)
    bfrag[ks] = *(const hs8*)&WT[(size_t)(col0 + lr) * 128 + ks * 32 + lk];
  int row0 = blockIdx.x * 64;
#pragma unroll 1
  for (int mt = 0; mt < 4; mt++) {
    int r0 = row0 + mt * 16;
    if (r0 >= NN) return;
    const _Float16* hr = h + (size_t)(r0 + lr) * 128 + lk;
    f32x4 acc = {0.f, 0.f, 0.f, 0.f};
#pragma unroll
    for (int ks = 0; ks < 4; ks++) {
      hs8 af = *(const hs8*)&hr[ks * 32];
      acc = MFMA16H(af, bfrag[ks], acc);
    }
    int rbase = r0 + (lane >> 4) * 4;
#pragma unroll
    for (int r = 0; r < 4; r++)
      t2[(size_t)(rbase + r) * 64 + col0 + lr] = (_Float16)acc[r];
  }
}

// ---------------- aggregation (2 nodes/wave, 2-deep load pipeline) ----------------

// layer 1: fp8 rows (128 B). half (32 lanes) per node; 2 subgroups of 16 per half.
// Pipeline: e0 (consume), e1 (gather in flight), e2 (wcsr in flight).
__global__ __launch_bounds__(256) void k_agg128(const unsigned char* __restrict__ t8, const int* __restrict__ offs,
                                                const int* __restrict__ deg, const uint2* __restrict__ wcsr,
                                                const float* __restrict__ bias, _Float16* __restrict__ out) {
  int wave = threadIdx.x >> 6, lane = threadIdx.x & 63;
  int half = lane >> 5;          // 0: node A, 1: node B
  int sub = (lane >> 4) & 1;     // edge parity within half
  int f = lane & 15;             // feature lane (8 fp8 feats)
  int node = blockIdx.x * 8 + wave * 2 + half;
  int beg = offs[node];
  int d = deg[node];             // includes self-loop
  const char* tb = (const char*)t8;
  f32x2 acc2[4] = {};
  int trips = (d + 1) >> 1;
  uint2 e0 = (sub < d) ? wcsr[beg + sub] : make_uint2(0u, 0u);
  int ns = 2 + sub;
  uint2 e1 = (ns < d) ? wcsr[beg + ns] : make_uint2(0u, 0u);
  uint2 u0 = *(const uint2*)(tb + (((size_t)e0.x) << 7) + (f << 3));
#pragma unroll 1
  for (int k = 0; k < trips; k++) {
    int n2 = (k + 2) * 2 + sub;
    uint2 e2 = (n2 < d) ? wcsr[beg + n2] : make_uint2(0u, 0u);
    uint2 u1 = *(const uint2*)(tb + (((size_t)e1.x) << 7) + (f << 3));
    float s = __uint_as_float(e0.y);  // 0 for padded slots
    f32x2 s2 = {s, s};
    f32x2 p0 = __builtin_amdgcn_cvt_pk_f32_fp8(u0.x, false);
    f32x2 p1 = __builtin_amdgcn_cvt_pk_f32_fp8(u0.x, true);
    f32x2 p2 = __builtin_amdgcn_cvt_pk_f32_fp8(u0.y, false);
    f32x2 p3 = __builtin_amdgcn_cvt_pk_f32_fp8(u0.y, true);
    acc2[0] = __builtin_elementwise_fma(p0, s2, acc2[0]);
    acc2[1] = __builtin_elementwise_fma(p1, s2, acc2[1]);
    acc2[2] = __builtin_elementwise_fma(p2, s2, acc2[2]);
    acc2[3] = __builtin_elementwise_fma(p3, s2, acc2[3]);
    e0 = e1; e1 = e2; u0 = u1;
  }
  float a[8];
#pragma unroll
  for (int j = 0; j < 4; j++) { a[2 * j] = acc2[j][0]; a[2 * j + 1] = acc2[j][1]; }
#pragma unroll
  for (int j = 0; j < 8; j++) a[j] += __shfl_xor(a[j], 16);
  if (sub == 0) {
    float4 b0 = *(const float4*)&bias[f * 8];
    float4 b1 = *(const float4*)&bias[f * 8 + 4];
    h8u st;
    st.h[0] = (_Float16)fmaxf(a[0] + b0.x, 0.f);
    st.h[1] = (_Float16)fmaxf(a[1] + b0.y, 0.f);
    st.h[2] = (_Float16)fmaxf(a[2] + b0.z, 0.f);
    st.h[3] = (_Float16)fmaxf(a[3] + b0.w, 0.f);
    st.h[4] = (_Float16)fmaxf(a[4] + b1.x, 0.f);
    st.h[5] = (_Float16)fmaxf(a[5] + b1.y, 0.f);
    st.h[6] = (_Float16)fmaxf(a[6] + b1.z, 0.f);
    st.h[7] = (_Float16)fmaxf(a[7] + b1.w, 0.f);
    *(uint4*)&out[(size_t)node * 128 + f * 8] = st.q;
  }
}

// layer 2: fp16 rows (128 B). half (32 lanes) per node; 4 subgroups of 8 per half.
__global__ __launch_bounds__(256) void k_agg64(const _Float16* __restrict__ t, const int* __restrict__ offs,
                                               const int* __restrict__ deg, const uint2* __restrict__ wcsr,
                                               const float* __restrict__ bias, float* __restrict__ out) {
  int wave = threadIdx.x >> 6, lane = threadIdx.x & 63;
  int half = lane >> 5;
  int sub = (lane >> 3) & 3;     // edge slot within half
  int f8 = lane & 7;             // feature lane (8 fp16 feats)
  int node = blockIdx.x * 8 + wave * 2 + half;
  int beg = offs[node];
  int d = deg[node];
  const char* tb = (const char*)t;
  float acc[8] = {};
  int trips = (d + 3) >> 2;
  uint2 e0 = (sub < d) ? wcsr[beg + sub] : make_uint2(0u, 0u);
  int ns = 4 + sub;
  uint2 e1 = (ns < d) ? wcsr[beg + ns] : make_uint2(0u, 0u);
  h8u u0;
  u0.q = *(const uint4*)(tb + (((size_t)e0.x) << 7) + (f8 << 4));
#pragma unroll 1
  for (int k = 0; k < trips; k++) {
    int n2 = (k + 2) * 4 + sub;
    uint2 e2 = (n2 < d) ? wcsr[beg + n2] : make_uint2(0u, 0u);
    h8u u1;
    u1.q = *(const uint4*)(tb + (((size_t)e1.x) << 7) + (f8 << 4));
    float s = __uint_as_float(e0.y);
    acc[0] = fmaf((float)u0.h[0], s, acc[0]);
    acc[1] = fmaf((float)u0.h[1], s, acc[1]);
    acc[2] = fmaf((float)u0.h[2], s, acc[2]);
    acc[3] = fmaf((float)u0.h[3], s, acc[3]);
    acc[4] = fmaf((float)u0.h[4], s, acc[4]);
    acc[5] = fmaf((float)u0.h[5], s, acc[5]);
    acc[6] = fmaf((float)u0.h[6], s, acc[6]);
    acc[7] = fmaf((float)u0.h[7], s, acc[7]);
    e0 = e1; e1 = e2; u0 = u1;
  }
#pragma unroll
  for (int j = 0; j < 8; j++) {
    acc[j] += __shfl_xor(acc[j], 8);
    acc[j] += __shfl_xor(acc[j], 16);
  }
  if (sub == 0) {
    float4 b0 = *(const float4*)&bias[f8 * 8];
    float4 b1 = *(const float4*)&bias[f8 * 8 + 4];
    float4 o0 = make_float4(acc[0] + b0.x, acc[1] + b0.y, acc[2] + b0.z, acc[3] + b0.w);
    float4 o1 = make_float4(acc[4] + b1.x, acc[5] + b1.y, acc[6] + b1.z, acc[7] + b1.w);
    *(float4*)&out[(size_t)node * 64 + f8 * 8] = o0;
    *(float4*)&out[(size_t)node * 64 + f8 * 8 + 4] = o1;
  }
}

// ---------------- host ----------------

extern "C" void kernel_launch(void* const* d_in, const int* in_sizes, int n_in,
                              void* d_out, int out_size, void* d_ws, size_t ws_size,
                              hipStream_t stream) {
  const float* x  = (const float*)d_in[0];
  const int*   ei = (const int*)d_in[1];
  const float* W1 = (const float*)d_in[2];
  const float* b1 = (const float*)d_in[3];
  const float* W2 = (const float*)d_in[4];
  const float* b2 = (const float*)d_in[5];
  float* out = (float*)d_out;

  char* p = (char*)d_ws;
  int* deg       = (int*)p;      p += alignup((size_t)NN * 4);
  int* gcur      = (int*)p;      p += alignup((size_t)NBUK * 4);
  int* offs      = (int*)p;      p += alignup((size_t)NN * 4);
  int* gtotal    = (int*)p;      p += alignup(256);
  float* dinv    = (float*)p;    p += alignup((size_t)NN * 4);
  uint2* wcsr    = (uint2*)p;    p += alignup((size_t)(NE + NN + 64) * 8);
  _Float16* WT1  = (_Float16*)p; p += alignup(128 * 128 * 2);
  _Float16* WT2  = (_Float16*)p; p += alignup(64 * 128 * 2);
  unsigned char* t8 = (unsigned char*)p; p += alignup((size_t)NN * 128);
  _Float16* t2   = (_Float16*)p; p += alignup((size_t)NN * 64 * 2);
  _Float16* h1   = (_Float16*)p; p += alignup((size_t)NN * 128 * 2);
  // packed pair buffer aliases t2 (dead until k_gemm64 writes it); 6.4 MB <= 12.8 MB
  uint* pr_pack  = (uint*)t2;
  (void)ws_size; (void)in_sizes; (void)n_in; (void)out_size;

  const int* row = ei;
  const int* col = ei + NE;

  int nbB = (NE + CHUNK - 1) / CHUNK;
  int nbG = (NN + 63) / 64;
  int nbA = NN / 8;

  k_prep0<<<97, 256, 0, stream>>>(gcur, gtotal, W1, WT1, W2, WT2);
  k_fused1<<<nbB + nbG, 256, 0, stream>>>(row, col, gcur, pr_pack, x, WT1, t8, nbB);
  k_bdeg<<<NBUK, 256, 0, stream>>>(pr_pack, gcur, deg, dinv);
  k_bfill<<<NBUK, 256, 0, stream>>>(pr_pack, gcur, deg, dinv, gtotal, offs, wcsr);
  k_agg128<<<nbA, 256, 0, stream>>>(t8, offs, deg, wcsr, b1, h1);
  k_gemm64<<<nbG, 256, 0, stream>>>(h1, WT2, t2);
  k_agg64<<<nbA, 256, 0, stream>>>(t2, offs, deg, wcsr, b2, out);
}